// Round 9
// baseline (4526.731 us; speedup 1.0000x reference)
//
#include <hip/hip_runtime.h>

#define LATENT 32
#define NN     100000
#define E1N    3200000
#define N2N    200000
#define E2N    3200000
#define MN     131072
#define MAXX   100
#define EPSV   1e-5f

#define BK_SH     7          // 128 nodes per bucket
#define PACK_SH   20         // src in bits 0..19, dst_local in bits 20..26
#define PACK_MASK 0xFFFFF
#define WIN_SH    15         // src-window = src >> 15  (32768 nodes = 4.19MB of h)
#define NBKT1     782        // ceil(100000/128)
#define NBKT2     1563       // ceil(200000/128)
#define P_PART    128        // partitions per edge list
#define CH        25000      // edges per partition (3.2M / 128)
#define MF_       200064     // NBKT2*128
#define MTOT      500224     // 2*MF_ + NBKT1*128
#define SCAN_NB   245        // ceil(MTOT/2048)
#define EDGE_CAP  4608       // LDS edge buffer for k_bwin

// ---------------- workspace layout (bytes) ----------------
constexpr size_t OFF_HA    = 0;                      // 25.6MB
constexpr size_t OFF_HB    = 25600000;               // 25.6MB (h1 in 1st half; be1 in 2nd half)
constexpr size_t OFF_BE1   = OFF_HB + 12800000;
constexpr size_t OFF_BEF   = 51200000;               // 12.8MB
constexpr size_t OFF_BER   = 64000000;               // 12.8MB
constexpr size_t OFF_CNT   = 76800000;               // 2.0MB; invdeg overlays after bfill
constexpr size_t OFF_IDF   = 76800000;               // invdegF  (N2N floats)
constexpr size_t OFF_IDR   = 77600000;               // invdegR  (N2N floats)
constexpr size_t OFF_ID1   = 78400000;               // invdeg1  (NN floats)
constexpr size_t OFF_BST   = 78801920;               // bstartF/R/1 (3911 ints)
constexpr size_t OFF_BSUM  = 78820352;
constexpr size_t OFF_HIST  = 78822400;
constexpr size_t OFF_WLP   = 78823424;
constexpr size_t OFF_WRP   = 78827520;
constexpr size_t OFF_BP    = 78831616;

// ---------------- x histogram + fused GraphNorm/weight prep ----------------

__global__ void k_histx(const int* __restrict__ x, int* __restrict__ hist, int n) {
    __shared__ int h[128];
    int t = threadIdx.x;
    if (t < 128) h[t] = 0;
    __syncthreads();
    int stride = gridDim.x * blockDim.x;
    for (int i = blockIdx.x * blockDim.x + t; i < n; i += stride)
        atomicAdd(&h[x[i]], 1);
    __syncthreads();
    if (t < 128 && h[t] > 0) atomicAdd(&hist[t], h[t]);
}

__global__ void k_prep(const int* __restrict__ hist, const float* __restrict__ emb,
                       const float* __restrict__ gw, const float* __restrict__ gb,
                       const float* __restrict__ gms,
                       const float* __restrict__ wl, const float* __restrict__ bl,
                       const float* __restrict__ wr,
                       float* __restrict__ wlp, float* __restrict__ wrp,
                       float* __restrict__ bp) {
    __shared__ float A[32], B[32];
    int t = threadIdx.x;
    if (t < 32) {
        float m = 0.f, q = 0.f;
        for (int c = 0; c <= MAXX; ++c) {
            float hc = (float)hist[c];
            float v  = emb[c * 32 + t];
            m += hc * v; q += hc * v * v;
        }
        m *= (1.f / (float)NN); q *= (1.f / (float)NN);
        float ms  = gms[t];
        float var = q - 2.f * ms * m * m + ms * ms * m * m;
        float a   = gw[t] / sqrtf(var + EPSV);
        A[t] = a;
        B[t] = gb[t] - a * ms * m;
    }
    __syncthreads();
    for (int i = t; i < 1024; i += 256) {
        int k = i & 31;
        wlp[i] = wl[i] * A[k];
        wrp[i] = wr[i] * A[k];
    }
    if (t < 32) {
        float s = bl[t];
        for (int k = 0; k < 32; ++k) s += (wl[t * 32 + k] + wr[t * 32 + k]) * B[k];
        bp[t] = s;
    }
}

// ---------------- partitioned counting-sort edge binning ----------------

__global__ void __launch_bounds__(256) k_hist(const int* __restrict__ dF,
                                              const int* __restrict__ dR,
                                              const int* __restrict__ d1,
                                              int* __restrict__ cnt) {
    __shared__ int hist[NBKT2];
    int t = threadIdx.x;
    int which = blockIdx.x >> 7, p = blockIdx.x & 127;
    const int* d; int nbkt, roff;
    if (which == 0)      { d = dF; nbkt = NBKT2; roff = 0; }
    else if (which == 1) { d = dR; nbkt = NBKT2; roff = MF_; }
    else                 { d = d1; nbkt = NBKT1; roff = 2 * MF_; }
    for (int b = t; b < nbkt; b += 256) hist[b] = 0;
    __syncthreads();
    int e0 = p * CH;
    for (int e = e0 + t; e < e0 + CH; e += 256)
        atomicAdd(&hist[d[e] >> BK_SH], 1);
    __syncthreads();
    for (int b = t; b < nbkt; b += 256) cnt[roff + (b << 7) + p] = hist[b];
}

__global__ void k_scanA(const int* __restrict__ cnt, int* __restrict__ bsum) {
    __shared__ int lds[256];
    int t = threadIdx.x;
    int base = blockIdx.x * 2048 + t * 8;
    int s = 0;
    #pragma unroll
    for (int j = 0; j < 8; ++j) { int e = base + j; if (e < MTOT) s += cnt[e]; }
    lds[t] = s; __syncthreads();
    for (int o = 128; o > 0; o >>= 1) { if (t < o) lds[t] += lds[t + o]; __syncthreads(); }
    if (t == 0) bsum[blockIdx.x] = lds[0];
}

__global__ void k_scanB(int* __restrict__ bsum, int nb) {
    __shared__ int lds[256];
    int t = threadIdx.x;
    int v = (t < nb) ? bsum[t] : 0;
    lds[t] = v; __syncthreads();
    for (int o = 1; o < 256; o <<= 1) {
        int add = (t >= o) ? lds[t - o] : 0;
        __syncthreads();
        lds[t] += add;
        __syncthreads();
    }
    if (t < nb) bsum[t] = lds[t] - v;
}

__global__ void k_scanC(int* __restrict__ cnt, const int* __restrict__ bsum) {
    __shared__ int lds[256];
    int t = threadIdx.x;
    int base = blockIdx.x * 2048 + t * 8;
    int v[8]; int run = 0;
    #pragma unroll
    for (int j = 0; j < 8; ++j) {
        int e = base + j;
        v[j] = (e < MTOT) ? cnt[e] : 0;
        run += v[j];
    }
    int tot = run;
    lds[t] = tot; __syncthreads();
    for (int o = 1; o < 256; o <<= 1) {
        int add = (t >= o) ? lds[t - o] : 0;
        __syncthreads();
        lds[t] += add;
        __syncthreads();
    }
    int ex = lds[t] - tot + bsum[blockIdx.x];
    #pragma unroll
    for (int j = 0; j < 8; ++j) {
        int e = base + j;
        if (e < MTOT) { cnt[e] = ex; ex += v[j]; }
    }
}

// extract per-bucket start offsets (cnt dies after k_bfill*)
__global__ void k_bstart(const int* __restrict__ cnt, int* __restrict__ bsF,
                         int* __restrict__ bsR, int* __restrict__ bs1) {
    int t = blockIdx.x * blockDim.x + threadIdx.x;
    int stride = gridDim.x * blockDim.x;
    for (int b = t; b <= NBKT2; b += stride) {
        bsF[b] = (b < NBKT2) ? cnt[b << 7] : E2N;
        bsR[b] = (b < NBKT2) ? cnt[MF_ + (b << 7)] - E2N : E2N;
    }
    for (int b = t; b <= NBKT1; b += stride)
        bs1[b] = (b < NBKT1) ? cnt[2 * MF_ + (b << 7)] - 2 * E2N : E1N;
}

__global__ void __launch_bounds__(256) k_bfillFR(
    const int* __restrict__ sF, const int* __restrict__ dF,
    const int* __restrict__ sR, const int* __restrict__ dR,
    const int* __restrict__ cnt, int* __restrict__ beF, int* __restrict__ beR) {
    __shared__ int cur[NBKT2];
    int t = threadIdx.x;
    int which = blockIdx.x >> 7, p = blockIdx.x & 127;
    const int* s; const int* d; int* be; int roff, sub;
    if (which == 0) { s = sF; d = dF; be = beF; roff = 0;   sub = 0; }
    else            { s = sR; d = dR; be = beR; roff = MF_; sub = E2N; }
    for (int b = t; b < NBKT2; b += 256) cur[b] = cnt[roff + (b << 7) + p] - sub;
    __syncthreads();
    int e0 = p * CH;
    for (int e = e0 + t; e < e0 + CH; e += 256) {
        int dd  = d[e];
        int pos = atomicAdd(&cur[dd >> BK_SH], 1);
        be[pos] = s[e] | ((dd & 127) << PACK_SH);
    }
}

__global__ void __launch_bounds__(256) k_bfill1(
    const int* __restrict__ s1, const int* __restrict__ d1,
    const int* __restrict__ cnt, int* __restrict__ be) {
    __shared__ int cur[NBKT1];
    int t = threadIdx.x;
    int p = blockIdx.x;
    for (int b = t; b < NBKT1; b += 256) cur[b] = cnt[2 * MF_ + (b << 7) + p] - 2 * E2N;
    __syncthreads();
    int e0 = p * CH;
    for (int e = e0 + t; e < e0 + CH; e += 256) {
        int dd  = d1[e];
        int pos = atomicAdd(&cur[dd >> BK_SH], 1);
        be[pos] = s1[e] | ((dd & 127) << PACK_SH);
    }
}

// per-bucket: sort edges by src-window (perf only) + emit 1/deg per node
__global__ void __launch_bounds__(256) k_bwin(
    int* __restrict__ beF, const int* __restrict__ bsF, float* __restrict__ invF,
    int* __restrict__ beR, const int* __restrict__ bsR, float* __restrict__ invR,
    int* __restrict__ be1, const int* __restrict__ bs1, float* __restrict__ inv1) {
    __shared__ int ebuf[EDGE_CAP];
    __shared__ int sbuf[EDGE_CAP];
    __shared__ int winh[8], wps[8], degh[128];
    int t = threadIdx.x;
    int blk = blockIdx.x;
    int* be; const int* bs; float* inv; int b, ntot;
    if (blk < NBKT2)            { be = beF; bs = bsF; inv = invF; b = blk;             ntot = N2N; }
    else if (blk < 2 * NBKT2)   { be = beR; bs = bsR; inv = invR; b = blk - NBKT2;     ntot = N2N; }
    else                        { be = be1; bs = bs1; inv = inv1; b = blk - 2 * NBKT2; ntot = NN; }
    int e0 = bs[b], e1 = bs[b + 1];
    int ne = e1 - e0;
    bool doSort = (ne <= EDGE_CAP);
    if (t < 8)  winh[t] = 0;
    if (t < 128) degh[t] = 0;
    __syncthreads();
    for (int e = t; e < ne; e += 256) {
        int w = be[e0 + e];
        if (doSort) ebuf[e] = w;
        atomicAdd(&degh[(w >> PACK_SH) & 127], 1);
        if (doSort) atomicAdd(&winh[(w & PACK_MASK) >> WIN_SH], 1);
    }
    __syncthreads();
    if (t == 0) {
        int r = 0;
        #pragma unroll
        for (int i = 0; i < 8; ++i) { wps[i] = r; r += winh[i]; }
    }
    int node = (b << BK_SH) + t;
    if (t < 128 && node < ntot) {
        int dg = degh[t];
        inv[node] = 1.0f / (float)(dg > 0 ? dg : 1);
    }
    __syncthreads();
    if (doSort) {
        for (int e = t; e < ne; e += 256) {
            int w   = ebuf[e];
            int pos = atomicAdd(&wps[(w & PACK_MASK) >> WIN_SH], 1);
            sbuf[pos] = w;
        }
        __syncthreads();
        for (int e = t; e < ne; e += 256) be[e0 + e] = sbuf[e];
    }
}

// ---------------- edge-centric bucket SAGE kernels ----------------

// aggregate one edge-list range into acc[128][32] via LDS float atomics
__device__ __forceinline__ void agg_edges(const float* __restrict__ hin,
                                          const int* __restrict__ be, int e0, int e1,
                                          float (*acc)[32], int lane, int grp) {
    int total = e1 - e0;
    int per = (total + 7) >> 3;
    int gs = e0 + grp * per;
    int ge = gs + per; if (ge > e1) ge = e1;
    for (int base = gs; base < ge; base += 32) {
        int e = base + lane;
        int w = be[e < ge ? e : ge - 1];
        int m = ge - base; if (m > 32) m = 32;
        for (int j = 0; j < m; j += 8) {
            float v[8]; int dl[8];
            #pragma unroll
            for (int k = 0; k < 8; ++k) {
                int wj = __shfl(w, (j + k) & 31, 32);
                int src = wj & PACK_MASK;
                dl[k] = (wj >> PACK_SH) & 127;
                v[k]  = hin[src * 32 + lane];
            }
            #pragma unroll
            for (int k = 0; k < 8; ++k)
                if (j + k < m) atomicAdd(&acc[dl[k]][lane], v[k]);
        }
    }
}

// conv1 layer 1: neighbors via emb[x[src]] (x gather 4B, emb in LDS)
__global__ void __launch_bounds__(256) k_bsage_emb(
    const int* __restrict__ x, const float* __restrict__ emb,
    float* __restrict__ hout,
    const int* __restrict__ be, const int* __restrict__ bs,
    const float* __restrict__ inv1,
    const float* __restrict__ wlp, const float* __restrict__ bp,
    const float* __restrict__ wrp) {
    __shared__ float embS[(MAXX + 1) * 32];
    __shared__ float wlT[32][33], wrT[32][33];
    __shared__ float acc[128][32];
    int t = threadIdx.x;
    for (int i = t; i < (MAXX + 1) * 32; i += 256) embS[i] = emb[i];
    for (int i = t; i < 1024; i += 256) {
        int j = i >> 5, k = i & 31;
        wlT[k][j] = wlp[i];
        wrT[k][j] = wrp[i];
    }
    for (int i = t; i < 4096; i += 256) acc[i >> 5][i & 31] = 0.f;
    __syncthreads();
    int lane = t & 31, grp = t >> 5;
    int b = blockIdx.x, node0 = b << BK_SH;
    int e0 = bs[b], e1 = bs[b + 1];
    {
        int total = e1 - e0;
        int per = (total + 7) >> 3;
        int gs = e0 + grp * per;
        int ge = gs + per; if (ge > e1) ge = e1;
        for (int base = gs; base < ge; base += 32) {
            int e = base + lane;
            int w = be[e < ge ? e : ge - 1];
            int m = ge - base; if (m > 32) m = 32;
            for (int j = 0; j < m; j += 8) {
                int xv[8]; int dl[8];
                #pragma unroll
                for (int k = 0; k < 8; ++k) {
                    int wj = __shfl(w, (j + k) & 31, 32);
                    dl[k] = (wj >> PACK_SH) & 127;
                    xv[k] = x[wj & PACK_MASK];
                }
                #pragma unroll
                for (int k = 0; k < 8; ++k)
                    if (j + k < m) atomicAdd(&acc[dl[k]][lane], embS[xv[k] * 32 + lane]);
            }
        }
    }
    __syncthreads();
    for (int d = grp; d < 128; d += 8) {
        int node = node0 + d;
        if (node >= NN) break;
        float s  = acc[d][lane] * inv1[node];
        float hs = embS[x[node] * 32 + lane];
        float a  = bp[lane];
        #pragma unroll
        for (int k = 0; k < 32; ++k) {
            a = fmaf(__shfl(s, k, 32), wlT[k][lane], a);
            a = fmaf(__shfl(hs, k, 32), wrT[k][lane], a);
        }
        hout[node * 32 + lane] = fmaxf(a, 0.f);
    }
}

// single-direction bucket sage (conv1 layer 2)
__global__ void __launch_bounds__(256) k_bsage1(
    const float* __restrict__ hin, float* __restrict__ hout,
    const int* __restrict__ be, const int* __restrict__ bs,
    const float* __restrict__ inv1,
    const float* __restrict__ wl, const float* __restrict__ bl,
    const float* __restrict__ wr, int ntot) {
    __shared__ float wlT[32][33], wrT[32][33];
    __shared__ float acc[128][32];
    int t = threadIdx.x;
    for (int i = t; i < 1024; i += 256) {
        int j = i >> 5, k = i & 31;
        wlT[k][j] = wl[i];
        wrT[k][j] = wr[i];
    }
    for (int i = t; i < 4096; i += 256) acc[i >> 5][i & 31] = 0.f;
    __syncthreads();
    int lane = t & 31, grp = t >> 5;
    int b = blockIdx.x, node0 = b << BK_SH;
    agg_edges(hin, be, bs[b], bs[b + 1], acc, lane, grp);
    __syncthreads();
    for (int d = grp; d < 128; d += 8) {
        int node = node0 + d;
        if (node >= ntot) break;
        float s  = acc[d][lane] * inv1[node];
        float hs = hin[node * 32 + lane];
        float a  = bl[lane];
        #pragma unroll
        for (int k = 0; k < 32; ++k) {
            a = fmaf(__shfl(s, k, 32), wlT[k][lane], a);
            a = fmaf(__shfl(hs, k, 32), wrT[k][lane], a);
        }
        hout[node * 32 + lane] = fmaxf(a, 0.f);
    }
}

// dual-direction bucket sage (conv2): relu(F) + relu(R)
__global__ void __launch_bounds__(256) k_bsage2(
    const float* __restrict__ hin, float* __restrict__ hout,
    const int* __restrict__ beF, const int* __restrict__ bsF, const float* __restrict__ invF,
    const int* __restrict__ beR, const int* __restrict__ bsR, const float* __restrict__ invR,
    const float* __restrict__ wlF, const float* __restrict__ blF, const float* __restrict__ wrF,
    const float* __restrict__ wlR, const float* __restrict__ blR, const float* __restrict__ wrR) {
    __shared__ float WLF[32][33], WRF[32][33], WLR[32][33], WRR[32][33];
    __shared__ float accF[128][32], accR[128][32];
    int t = threadIdx.x;
    for (int i = t; i < 1024; i += 256) {
        int j = i >> 5, k = i & 31;
        WLF[k][j] = wlF[i];
        WRF[k][j] = wrF[i];
        WLR[k][j] = wlR[i];
        WRR[k][j] = wrR[i];
    }
    for (int i = t; i < 4096; i += 256) {
        accF[i >> 5][i & 31] = 0.f;
        accR[i >> 5][i & 31] = 0.f;
    }
    __syncthreads();
    int lane = t & 31, grp = t >> 5;
    int b = blockIdx.x, node0 = b << BK_SH;
    agg_edges(hin, beF, bsF[b], bsF[b + 1], accF, lane, grp);
    agg_edges(hin, beR, bsR[b], bsR[b + 1], accR, lane, grp);
    __syncthreads();
    for (int d = grp; d < 128; d += 8) {
        int node = node0 + d;
        if (node >= N2N) break;
        float sF = accF[d][lane] * invF[node];
        float sR = accR[d][lane] * invR[node];
        float hs = hin[node * 32 + lane];
        float aF = blF[lane];
        float aR = blR[lane];
        #pragma unroll
        for (int k = 0; k < 32; ++k) {
            float fk = __shfl(sF, k, 32);
            float rk = __shfl(sR, k, 32);
            float hk = __shfl(hs, k, 32);
            aF = fmaf(fk, WLF[k][lane], aF);
            aF = fmaf(hk, WRF[k][lane], aF);
            aR = fmaf(rk, WLR[k][lane], aR);
            aR = fmaf(hk, WRR[k][lane], aR);
        }
        hout[node * 32 + lane] = fmaxf(aF, 0.f) + fmaxf(aR, 0.f);
    }
}

__global__ void k_pair(const float* __restrict__ h, const int* __restrict__ pos1,
                       float* __restrict__ hp, int total) {
    int idx = blockIdx.x * blockDim.x + threadIdx.x;
    int stride = gridDim.x * blockDim.x;
    for (; idx < total; idx += stride) {
        int r = idx >> 5, k = idx & 31;
        int a = pos1[2 * r], b = pos1[2 * r + 1];
        hp[idx] = h[a * 32 + k] * h[b * 32 + k];
    }
}

__global__ void k_final(const float* __restrict__ h, const int* __restrict__ pos2,
                        const float* __restrict__ pw, const float* __restrict__ pb,
                        float* __restrict__ out, int m2) {
    int tid  = threadIdx.x;
    int lane = tid & 31;
    int i    = blockIdx.x * 8 + (tid >> 5);
    if (i >= m2) return;
    int p0 = pos2[2 * i], p1 = pos2[2 * i + 1];
    float v = h[p0 * 32 + lane] * h[p1 * 32 + lane] * pw[lane];
    #pragma unroll
    for (int o = 16; o > 0; o >>= 1) v += __shfl_xor(v, o, 32);
    if (lane == 0) out[i] = v + pb[0];
}

// ---------------- launch ----------------

extern "C" void kernel_launch(void* const* d_in, const int* in_sizes, int n_in,
                              void* d_out, int out_size, void* d_ws, size_t ws_size,
                              hipStream_t stream) {
    const int*   x      = (const int*)d_in[0];
    const int*   edge1  = (const int*)d_in[2];
    const int*   edge2  = (const int*)d_in[3];
    const int*   edge2r = (const int*)d_in[4];
    const int*   pos1   = (const int*)d_in[5];
    const int*   pos2   = (const int*)d_in[6];
    const float* emb    = (const float*)d_in[7];
    const float* gw     = (const float*)d_in[8];
    const float* gb     = (const float*)d_in[9];
    const float* gms    = (const float*)d_in[10];
    const float* c1wl   = (const float*)d_in[11];
    const float* c1bl   = (const float*)d_in[12];
    const float* c1wr   = (const float*)d_in[13];
    const float* c2wl   = (const float*)d_in[14];
    const float* c2bl   = (const float*)d_in[15];
    const float* c2wr   = (const float*)d_in[16];
    const float* c2rwl  = (const float*)d_in[17];
    const float* c2rbl  = (const float*)d_in[18];
    const float* c2rwr  = (const float*)d_in[19];
    const float* pw     = (const float*)d_in[20];
    const float* pb     = (const float*)d_in[21];
    float* out = (float*)d_out;

    char* ws = (char*)d_ws;
    float* hA    = (float*)(ws + OFF_HA);
    float* hB    = (float*)(ws + OFF_HB);
    int*   be1   = (int*)(ws + OFF_BE1);
    int*   beF   = (int*)(ws + OFF_BEF);
    int*   beR   = (int*)(ws + OFF_BER);
    int*   cnt   = (int*)(ws + OFF_CNT);
    float* invF  = (float*)(ws + OFF_IDF);
    float* invR  = (float*)(ws + OFF_IDR);
    float* inv1  = (float*)(ws + OFF_ID1);
    int*   bsF   = (int*)(ws + OFF_BST);
    int*   bsR   = bsF + (NBKT2 + 1);
    int*   bs1   = bsR + (NBKT2 + 1);
    int*   bsum  = (int*)(ws + OFF_BSUM);
    int*   hist  = (int*)(ws + OFF_HIST);
    float* wlp   = (float*)(ws + OFF_WLP);
    float* wrp   = (float*)(ws + OFF_WRP);
    float* bp    = (float*)(ws + OFF_BP);

    hipMemsetAsync(hist, 0, 512, stream);

    // GraphNorm stats + layer-1 weight fold
    k_histx<<<256, 256, 0, stream>>>(x, hist, NN);
    k_prep<<<1, 256, 0, stream>>>(hist, emb, gw, gb, gms, c1wl, c1bl, c1wr, wlp, wrp, bp);

    // edge binning: hist -> scan -> bucket starts -> fill -> window-sort + invdeg
    k_hist<<<3 * P_PART, 256, 0, stream>>>(edge2 + E2N, edge2r + E2N, edge1 + E1N, cnt);
    k_scanA<<<SCAN_NB, 256, 0, stream>>>(cnt, bsum);
    k_scanB<<<1, 256, 0, stream>>>(bsum, SCAN_NB);
    k_scanC<<<SCAN_NB, 256, 0, stream>>>(cnt, bsum);
    k_bstart<<<16, 256, 0, stream>>>(cnt, bsF, bsR, bs1);
    k_bfillFR<<<2 * P_PART, 256, 0, stream>>>(edge2, edge2 + E2N, edge2r, edge2r + E2N,
                                              cnt, beF, beR);
    k_bfill1<<<P_PART, 256, 0, stream>>>(edge1, edge1 + E1N, cnt, be1);
    k_bwin<<<2 * NBKT2 + NBKT1, 256, 0, stream>>>(beF, bsF, invF, beR, bsR, invR,
                                                  be1, bs1, inv1);

    // conv1: emb-direct layer -> hB[0:12.8M); layer2 -> hA[0:12.8M)
    k_bsage_emb<<<NBKT1, 256, 0, stream>>>(x, emb, hB, be1, bs1, inv1, wlp, bp, wrp);
    k_bsage1<<<NBKT1, 256, 0, stream>>>(hB, hA, be1, bs1, inv1,
                                        c1wl + 1024, c1bl + 32, c1wr + 1024, NN);

    // pair features: hA -> hB (clobbers h1 + be1, both dead)
    k_pair<<<2048, 256, 0, stream>>>(hA, pos1, hB, N2N * 32);

    // conv2: hB -> hA -> hB
    k_bsage2<<<NBKT2, 256, 0, stream>>>(hB, hA, beF, bsF, invF, beR, bsR, invR,
        c2wl, c2bl, c2wr, c2rwl, c2rbl, c2rwr);
    k_bsage2<<<NBKT2, 256, 0, stream>>>(hA, hB, beF, bsF, invF, beR, bsR, invR,
        c2wl + 1024, c2bl + 32, c2wr + 1024, c2rwl + 1024, c2rbl + 32, c2rwr + 1024);

    // head
    k_final<<<(MN / 2) / 8, 256, 0, stream>>>(hB, pos2, pw, pb, out, MN / 2);
}

// Round 10
// 976.769 us; speedup vs baseline: 4.6344x; 4.6344x over previous
//
#include <hip/hip_runtime.h>

#define LATENT 32
#define NN     100000
#define E1N    3200000
#define N2N    200000
#define E2N    3200000
#define MN     131072
#define MAXX   100
#define EPSV   1e-5f

#define BK_SH     7          // 128 nodes per bucket
#define PACK_SH   20         // src in bits 0..19, dst_local in bits 20..26
#define PACK_MASK 0xFFFFF
#define WIN_SH    15         // src-window = src >> 15
#define NBKT1     782        // ceil(100000/128)
#define NBKT2     1563       // ceil(200000/128)
#define P_PART    128        // partitions per edge list
#define CH        25000      // edges per partition (3.2M / 128)
#define MF_       200064     // NBKT2*128
#define MTOT      500224     // 2*MF_ + NBKT1*128
#define SCAN_NB   245        // ceil(MTOT/2048)
#define ECAP      5120       // LDS edge buffer for sorted bcsr path

// ---------------- workspace layout (bytes) ----------------
constexpr size_t OFF_HA    = 0;
constexpr size_t OFF_HB    = 25600000;
constexpr size_t OFF_CSR1  = OFF_HB + 12800000;
constexpr size_t OFF_CSR2  = 51200000;
constexpr size_t OFF_CSR2R = 64000000;
constexpr size_t OFF_OFF1  = 76800000;
constexpr size_t OFF_OFF2  = OFF_OFF1 + 400128;
constexpr size_t OFF_OFF2R = OFF_OFF2 + 800128;
constexpr size_t OFF_BSUM  = OFF_OFF2R + 800128;
constexpr size_t OFF_HIST  = OFF_BSUM + 2048;
constexpr size_t OFF_WLP   = OFF_HIST + 512;
constexpr size_t OFF_WRP   = OFF_WLP + 4096;
constexpr size_t OFF_BP    = OFF_WRP + 4096;

// ---------------- x histogram + fused GraphNorm/weight prep ----------------

__global__ void k_histx(const int* __restrict__ x, int* __restrict__ hist, int n) {
    __shared__ int h[128];
    int t = threadIdx.x;
    if (t < 128) h[t] = 0;
    __syncthreads();
    int stride = gridDim.x * blockDim.x;
    for (int i = blockIdx.x * blockDim.x + t; i < n; i += stride)
        atomicAdd(&h[x[i]], 1);
    __syncthreads();
    if (t < 128 && h[t] > 0) atomicAdd(&hist[t], h[t]);
}

__global__ void k_prep(const int* __restrict__ hist, const float* __restrict__ emb,
                       const float* __restrict__ gw, const float* __restrict__ gb,
                       const float* __restrict__ gms,
                       const float* __restrict__ wl, const float* __restrict__ bl,
                       const float* __restrict__ wr,
                       float* __restrict__ wlp, float* __restrict__ wrp,
                       float* __restrict__ bp) {
    __shared__ float A[32], B[32];
    int t = threadIdx.x;
    if (t < 32) {
        float m = 0.f, q = 0.f;
        for (int c = 0; c <= MAXX; ++c) {
            float hc = (float)hist[c];
            float v  = emb[c * 32 + t];
            m += hc * v; q += hc * v * v;
        }
        m *= (1.f / (float)NN); q *= (1.f / (float)NN);
        float ms  = gms[t];
        float var = q - 2.f * ms * m * m + ms * ms * m * m;
        float a   = gw[t] / sqrtf(var + EPSV);
        A[t] = a;
        B[t] = gb[t] - a * ms * m;
    }
    __syncthreads();
    for (int i = t; i < 1024; i += 256) {
        int k = i & 31;
        wlp[i] = wl[i] * A[k];
        wrp[i] = wr[i] * A[k];
    }
    if (t < 32) {
        float s = bl[t];
        for (int k = 0; k < 32; ++k) s += (wl[t * 32 + k] + wr[t * 32 + k]) * B[k];
        bp[t] = s;
    }
}

// ---------------- partitioned counting-sort CSR build ----------------

__global__ void __launch_bounds__(256) k_hist(const int* __restrict__ dF,
                                              const int* __restrict__ dR,
                                              const int* __restrict__ d1,
                                              int* __restrict__ cnt) {
    __shared__ int hist[NBKT2];
    int t = threadIdx.x;
    int which = blockIdx.x >> 7, p = blockIdx.x & 127;
    const int* d; int nbkt, roff;
    if (which == 0)      { d = dF; nbkt = NBKT2; roff = 0; }
    else if (which == 1) { d = dR; nbkt = NBKT2; roff = MF_; }
    else                 { d = d1; nbkt = NBKT1; roff = 2 * MF_; }
    for (int b = t; b < nbkt; b += 256) hist[b] = 0;
    __syncthreads();
    int e0 = p * CH;
    for (int e = e0 + t; e < e0 + CH; e += 256)
        atomicAdd(&hist[d[e] >> BK_SH], 1);
    __syncthreads();
    for (int b = t; b < nbkt; b += 256) cnt[roff + (b << 7) + p] = hist[b];
}

__global__ void k_scanA(const int* __restrict__ cnt, int* __restrict__ bsum) {
    __shared__ int lds[256];
    int t = threadIdx.x;
    int base = blockIdx.x * 2048 + t * 8;
    int s = 0;
    #pragma unroll
    for (int j = 0; j < 8; ++j) { int e = base + j; if (e < MTOT) s += cnt[e]; }
    lds[t] = s; __syncthreads();
    for (int o = 128; o > 0; o >>= 1) { if (t < o) lds[t] += lds[t + o]; __syncthreads(); }
    if (t == 0) bsum[blockIdx.x] = lds[0];
}

__global__ void k_scanB(int* __restrict__ bsum, int nb) {
    __shared__ int lds[256];
    int t = threadIdx.x;
    int v = (t < nb) ? bsum[t] : 0;
    lds[t] = v; __syncthreads();
    for (int o = 1; o < 256; o <<= 1) {
        int add = (t >= o) ? lds[t - o] : 0;
        __syncthreads();
        lds[t] += add;
        __syncthreads();
    }
    if (t < nb) bsum[t] = lds[t] - v;
}

__global__ void k_scanC(int* __restrict__ cnt, const int* __restrict__ bsum) {
    __shared__ int lds[256];
    int t = threadIdx.x;
    int base = blockIdx.x * 2048 + t * 8;
    int v[8]; int run = 0;
    #pragma unroll
    for (int j = 0; j < 8; ++j) {
        int e = base + j;
        v[j] = (e < MTOT) ? cnt[e] : 0;
        run += v[j];
    }
    int tot = run;
    lds[t] = tot; __syncthreads();
    for (int o = 1; o < 256; o <<= 1) {
        int add = (t >= o) ? lds[t - o] : 0;
        __syncthreads();
        lds[t] += add;
        __syncthreads();
    }
    int ex = lds[t] - tot + bsum[blockIdx.x];
    #pragma unroll
    for (int j = 0; j < 8; ++j) {
        int e = base + j;
        if (e < MTOT) { cnt[e] = ex; ex += v[j]; }
    }
}

__global__ void __launch_bounds__(256) k_bfillFR(
    const int* __restrict__ sF, const int* __restrict__ dF,
    const int* __restrict__ sR, const int* __restrict__ dR,
    const int* __restrict__ cnt, int* __restrict__ beF, int* __restrict__ beR) {
    __shared__ int cur[NBKT2];
    int t = threadIdx.x;
    int which = blockIdx.x >> 7, p = blockIdx.x & 127;
    const int* s; const int* d; int* be; int roff, sub;
    if (which == 0) { s = sF; d = dF; be = beF; roff = 0;   sub = 0; }
    else            { s = sR; d = dR; be = beR; roff = MF_; sub = E2N; }
    for (int b = t; b < NBKT2; b += 256) cur[b] = cnt[roff + (b << 7) + p] - sub;
    __syncthreads();
    int e0 = p * CH;
    for (int e = e0 + t; e < e0 + CH; e += 256) {
        int dd  = d[e];
        int pos = atomicAdd(&cur[dd >> BK_SH], 1);
        be[pos] = s[e] | ((dd & 127) << PACK_SH);
    }
}

__global__ void __launch_bounds__(256) k_bfill1(
    const int* __restrict__ s1, const int* __restrict__ d1,
    const int* __restrict__ cnt, int* __restrict__ be) {
    __shared__ int cur[NBKT1];
    int t = threadIdx.x;
    int p = blockIdx.x;
    for (int b = t; b < NBKT1; b += 256) cur[b] = cnt[2 * MF_ + (b << 7) + p] - 2 * E2N;
    __syncthreads();
    int e0 = p * CH;
    for (int e = e0 + t; e < e0 + CH; e += 256) {
        int dd  = d1[e];
        int pos = atomicAdd(&cur[dd >> BK_SH], 1);
        be[pos] = s1[e] | ((dd & 127) << PACK_SH);
    }
}

// per-bucket refine with (node, src-window) two-key LDS counting sort:
// csr lists come out per-node, src-window-ascending (better gather locality)
__device__ __forceinline__ void bcsr_body(const int* __restrict__ bedge,
                                          const int* __restrict__ cnt, int roff, int sub,
                                          int* __restrict__ off, int* __restrict__ csr,
                                          int b, int nbkt, int ntot, int etot) {
    __shared__ int ebuf[ECAP];
    __shared__ int kcnt[1024];
    __shared__ int psum[256];
    int t  = threadIdx.x;
    int e0 = cnt[roff + (b << 7)] - sub;
    int e1 = (b + 1 < nbkt) ? cnt[roff + ((b + 1) << 7)] - sub : etot;
    int ne = e1 - e0;
    int node0 = b << BK_SH;
    int nloc  = ntot - node0; if (nloc > 128) nloc = 128;
    if (b == nbkt - 1 && t == 0) off[ntot] = e1;

    if (ne <= ECAP) {
        // ---- sorted path ----
        for (int i = t; i < 1024; i += 256) kcnt[i] = 0;
        __syncthreads();
        for (int e = t; e < ne; e += 256) {
            int w = bedge[e0 + e];
            ebuf[e] = w;
            int key = (((w >> PACK_SH) & 127) << 3) | ((w & PACK_MASK) >> WIN_SH);
            atomicAdd(&kcnt[key], 1);
        }
        __syncthreads();
        // scan 1024 keys: per-thread sum of 4, block scan, write back
        int v0 = kcnt[4 * t], v1 = kcnt[4 * t + 1], v2 = kcnt[4 * t + 2], v3 = kcnt[4 * t + 3];
        int tot = v0 + v1 + v2 + v3;
        psum[t] = tot;
        __syncthreads();
        for (int o = 1; o < 256; o <<= 1) {
            int add = (t >= o) ? psum[t - o] : 0;
            __syncthreads();
            psum[t] += add;
            __syncthreads();
        }
        int base = psum[t] - tot;
        kcnt[4 * t]     = base;
        kcnt[4 * t + 1] = base + v0;
        kcnt[4 * t + 2] = base + v0 + v1;
        kcnt[4 * t + 3] = base + v0 + v1 + v2;
        __syncthreads();
        if (t < nloc) off[node0 + t] = e0 + kcnt[t << 3];
        __syncthreads();
        for (int e = t; e < ne; e += 256) {
            int w   = ebuf[e];
            int key = (((w >> PACK_SH) & 127) << 3) | ((w & PACK_MASK) >> WIN_SH);
            int pos = atomicAdd(&kcnt[key], 1);
            csr[e0 + pos] = w & PACK_MASK;
        }
    } else {
        // ---- fallback: unsorted per-node placement ----
        int* lcnt = kcnt;
        int* exs  = kcnt + 128;
        int* sc   = kcnt + 256;
        if (t < 128) lcnt[t] = 0;
        __syncthreads();
        for (int e = e0 + t; e < e1; e += 256)
            atomicAdd(&lcnt[(bedge[e] >> PACK_SH) & 127], 1);
        __syncthreads();
        int cv = (t < 128) ? lcnt[t] : 0;
        if (t < 128) sc[t] = cv;
        __syncthreads();
        for (int o = 1; o < 128; o <<= 1) {
            int add = (t < 128 && t >= o) ? sc[t - o] : 0;
            __syncthreads();
            if (t < 128) sc[t] += add;
            __syncthreads();
        }
        if (t < 128) exs[t] = sc[t] - cv;
        __syncthreads();
        if (t < nloc) off[node0 + t] = e0 + exs[t];
        if (t < 128) lcnt[t] = 0;
        __syncthreads();
        for (int e = e0 + t; e < e1; e += 256) {
            int p   = bedge[e];
            int dl  = (p >> PACK_SH) & 127;
            int pos = e0 + exs[dl] + atomicAdd(&lcnt[dl], 1);
            csr[pos] = p & PACK_MASK;
        }
    }
}

__global__ void __launch_bounds__(256) k_bcsr2(
    const int* beF, const int* beR, const int* __restrict__ cnt,
    int* offF, int* csrF, int* offR, int* csrR) {
    int b = blockIdx.x;
    if (b < NBKT2) bcsr_body(beF, cnt, 0,   0,   offF, csrF, b,         NBKT2, N2N, E2N);
    else           bcsr_body(beR, cnt, MF_, E2N, offR, csrR, b - NBKT2, NBKT2, N2N, E2N);
}

__global__ void __launch_bounds__(256) k_bcsr1(
    const int* be, const int* __restrict__ cnt, int* off, int* csr) {
    bcsr_body(be, cnt, 2 * MF_, 2 * E2N, off, csr, blockIdx.x, NBKT1, NN, E1N);
}

// ---------------- conv1 layer 1: LDS emb table, 4B x-gathers ----------------

__global__ void __launch_bounds__(256) k_sage_emb(
    const int* __restrict__ x, const float* __restrict__ emb,
    float* __restrict__ hout,
    const int* __restrict__ csr, const int* __restrict__ off,
    const float* __restrict__ wlp, const float* __restrict__ bp,
    const float* __restrict__ wrp, int n) {
    __shared__ float embS[(MAXX + 1) * 32];
    __shared__ float wlT[32][33];
    __shared__ float wrT[32][33];
    int tid = threadIdx.x;
    for (int i = tid; i < (MAXX + 1) * 32; i += 256) embS[i] = emb[i];
    for (int i = tid; i < 1024; i += 256) {
        int j = i >> 5, k = i & 31;
        wlT[k][j] = wlp[i];
        wrT[k][j] = wrp[i];
    }
    __syncthreads();
    int lane = tid & 31;
    int g    = blockIdx.x * 8 + (tid >> 5);
    int G    = gridDim.x * 8;
    for (int node = g; node < n; node += G) {
        int s0 = off[node], s1 = off[node + 1];
        float a0 = 0.f, a1 = 0.f, a2 = 0.f, a3 = 0.f;
        for (int base = s0; base < s1; base += 32) {
            int e  = base + lane;
            int xv = x[csr[e < s1 ? e : s1 - 1]];
            int m  = s1 - base; if (m > 32) m = 32;
            for (int j = 0; j < m; j += 4) {
                #pragma unroll
                for (int k = 0; k < 4; ++k) {
                    int jj = j + k;
                    int xj = __shfl(xv, jj & 31, 32);
                    float v = embS[xj * 32 + lane];
                    float w = (jj < m) ? 1.f : 0.f;
                    switch (k) {
                        case 0: a0 = fmaf(v, w, a0); break;
                        case 1: a1 = fmaf(v, w, a1); break;
                        case 2: a2 = fmaf(v, w, a2); break;
                        case 3: a3 = fmaf(v, w, a3); break;
                    }
                }
            }
        }
        int c = s1 - s0;
        float s = ((a0 + a1) + (a2 + a3)) * (1.0f / (float)(c > 0 ? c : 1));
        float hs = embS[x[node] * 32 + lane];
        float acc = bp[lane];
        #pragma unroll
        for (int k = 0; k < 32; ++k) {
            acc = fmaf(__shfl(s, k, 32), wlT[k][lane], acc);
            acc = fmaf(__shfl(hs, k, 32), wrT[k][lane], acc);
        }
        hout[node * 32 + lane] = fmaxf(acc, 0.f);
    }
}

// ---------------- sage kernels ----------------

__device__ __forceinline__ void seg_mean_quad(
    const float* __restrict__ hin,
    const int* __restrict__ cA, int a0, int a1,
    const int* __restrict__ cB, int b0, int b1,
    const int* __restrict__ cC, int c0, int c1,
    const int* __restrict__ cD, int d0, int d1,
    int lane, float& oA, float& oB, float& oC, float& oD)
{
    float aA[4], aB[4], aC[4], aD[4];
    #pragma unroll
    for (int k = 0; k < 4; ++k) { aA[k] = 0.f; aB[k] = 0.f; aC[k] = 0.f; aD[k] = 0.f; }
    int pA = a0, pB = b0, pC = c0, pD = d0;
    while (pA < a1 || pB < b1 || pC < c1 || pD < d1) {
        int iA = 0, iB = 0, iC = 0, iD = 0, mA = 0, mB = 0, mC = 0, mD = 0;
        if (pA < a1) { int e = pA + lane; iA = cA[e < a1 ? e : a1 - 1]; mA = a1 - pA; if (mA > 32) mA = 32; }
        if (pB < b1) { int e = pB + lane; iB = cB[e < b1 ? e : b1 - 1]; mB = b1 - pB; if (mB > 32) mB = 32; }
        if (pC < c1) { int e = pC + lane; iC = cC[e < c1 ? e : c1 - 1]; mC = c1 - pC; if (mC > 32) mC = 32; }
        if (pD < d1) { int e = pD + lane; iD = cD[e < d1 ? e : d1 - 1]; mD = d1 - pD; if (mD > 32) mD = 32; }
        int mm = mA > mB ? mA : mB;
        if (mC > mm) mm = mC;
        if (mD > mm) mm = mD;
        for (int j = 0; j < mm; j += 8) {
            float vA[8], vB[8], vC[8], vD[8];
            bool dA = j < mA, dB = j < mB, dC = j < mC, dD = j < mD;
            if (dA) {
                #pragma unroll
                for (int k = 0; k < 8; ++k)
                    vA[k] = hin[__shfl(iA, (j + k) & 31, 32) * 32 + lane];
            }
            if (dB) {
                #pragma unroll
                for (int k = 0; k < 8; ++k)
                    vB[k] = hin[__shfl(iB, (j + k) & 31, 32) * 32 + lane];
            }
            if (dC) {
                #pragma unroll
                for (int k = 0; k < 8; ++k)
                    vC[k] = hin[__shfl(iC, (j + k) & 31, 32) * 32 + lane];
            }
            if (dD) {
                #pragma unroll
                for (int k = 0; k < 8; ++k)
                    vD[k] = hin[__shfl(iD, (j + k) & 31, 32) * 32 + lane];
            }
            if (dA) {
                #pragma unroll
                for (int k = 0; k < 8; ++k)
                    aA[k & 3] = fmaf(vA[k], (j + k < mA) ? 1.f : 0.f, aA[k & 3]);
            }
            if (dB) {
                #pragma unroll
                for (int k = 0; k < 8; ++k)
                    aB[k & 3] = fmaf(vB[k], (j + k < mB) ? 1.f : 0.f, aB[k & 3]);
            }
            if (dC) {
                #pragma unroll
                for (int k = 0; k < 8; ++k)
                    aC[k & 3] = fmaf(vC[k], (j + k < mC) ? 1.f : 0.f, aC[k & 3]);
            }
            if (dD) {
                #pragma unroll
                for (int k = 0; k < 8; ++k)
                    aD[k & 3] = fmaf(vD[k], (j + k < mD) ? 1.f : 0.f, aD[k & 3]);
            }
        }
        pA += 32; pB += 32; pC += 32; pD += 32;
    }
    int nA = a1 - a0, nB = b1 - b0, nC = c1 - c0, nD = d1 - d0;
    oA = ((aA[0] + aA[1]) + (aA[2] + aA[3])) * (1.0f / (float)(nA > 0 ? nA : 1));
    oB = ((aB[0] + aB[1]) + (aB[2] + aB[3])) * (1.0f / (float)(nB > 0 ? nB : 1));
    oC = ((aC[0] + aC[1]) + (aC[2] + aC[3])) * (1.0f / (float)(nC > 0 ? nC : 1));
    oD = ((aD[0] + aD[1]) + (aD[2] + aD[3])) * (1.0f / (float)(nD > 0 ? nD : 1));
}

__global__ void __launch_bounds__(256) k_sage(
    const float* __restrict__ hin, float* __restrict__ hout,
    const int* __restrict__ csr, const int* __restrict__ off,
    const float* __restrict__ wl, const float* __restrict__ bl, const float* __restrict__ wr,
    int n) {
    __shared__ float wlT[32][33];
    __shared__ float wrT[32][33];
    int tid = threadIdx.x;
    for (int idx = tid; idx < 1024; idx += 256) {
        int j = idx >> 5, k = idx & 31;
        wlT[k][j] = wl[idx];
        wrT[k][j] = wr[idx];
    }
    __syncthreads();
    int lane = tid & 31;
    int g    = blockIdx.x * 8 + (tid >> 5);
    int G    = gridDim.x * 8;
    for (int i = 4 * g; i < n; i += 4 * G) {
        int n0 = i, n1 = i + 1, n2 = i + 2, n3 = i + 3;
        float s0, s1, s2, s3;
        seg_mean_quad(hin, csr, off[n0], off[n0 + 1], csr, off[n1], off[n1 + 1],
                      csr, off[n2], off[n2 + 1], csr, off[n3], off[n3 + 1],
                      lane, s0, s1, s2, s3);
        float h0 = hin[n0 * 32 + lane];
        float h1 = hin[n1 * 32 + lane];
        float h2 = hin[n2 * 32 + lane];
        float h3 = hin[n3 * 32 + lane];
        float bb = bl[lane];
        float A0 = bb, A1 = bb, A2 = bb, A3 = bb;
        #pragma unroll
        for (int k = 0; k < 32; ++k) {
            float wlk = wlT[k][lane], wrk = wrT[k][lane];
            A0 = fmaf(__shfl(s0, k, 32), wlk, A0);
            A0 = fmaf(__shfl(h0, k, 32), wrk, A0);
            A1 = fmaf(__shfl(s1, k, 32), wlk, A1);
            A1 = fmaf(__shfl(h1, k, 32), wrk, A1);
            A2 = fmaf(__shfl(s2, k, 32), wlk, A2);
            A2 = fmaf(__shfl(h2, k, 32), wrk, A2);
            A3 = fmaf(__shfl(s3, k, 32), wlk, A3);
            A3 = fmaf(__shfl(h3, k, 32), wrk, A3);
        }
        hout[n0 * 32 + lane] = fmaxf(A0, 0.f);
        hout[n1 * 32 + lane] = fmaxf(A1, 0.f);
        hout[n2 * 32 + lane] = fmaxf(A2, 0.f);
        hout[n3 * 32 + lane] = fmaxf(A3, 0.f);
    }
}

__global__ void __launch_bounds__(256) k_sage2(
    const float* __restrict__ hin, float* __restrict__ hout,
    const int* __restrict__ csrF, const int* __restrict__ offF,
    const int* __restrict__ csrR, const int* __restrict__ offR,
    const float* __restrict__ wlF, const float* __restrict__ blF, const float* __restrict__ wrF,
    const float* __restrict__ wlR, const float* __restrict__ blR, const float* __restrict__ wrR,
    int n) {
    __shared__ float WLF[32][33], WRF[32][33], WLR[32][33], WRR[32][33];
    int tid = threadIdx.x;
    for (int idx = tid; idx < 1024; idx += 256) {
        int j = idx >> 5, k = idx & 31;
        WLF[k][j] = wlF[idx];
        WRF[k][j] = wrF[idx];
        WLR[k][j] = wlR[idx];
        WRR[k][j] = wrR[idx];
    }
    __syncthreads();
    int lane = tid & 31;
    int g    = blockIdx.x * 8 + (tid >> 5);
    int G    = gridDim.x * 8;
    for (int i = 2 * g; i < n; i += 2 * G) {
        int n0 = i, n1 = i + 1;
        float sF0, sR0, sF1, sR1;
        seg_mean_quad(hin, csrF, offF[n0], offF[n0 + 1], csrR, offR[n0], offR[n0 + 1],
                      csrF, offF[n1], offF[n1 + 1], csrR, offR[n1], offR[n1 + 1],
                      lane, sF0, sR0, sF1, sR1);
        float h0 = hin[n0 * 32 + lane];
        float h1 = hin[n1 * 32 + lane];
        float bF = blF[lane], bR = blR[lane];
        float aF0 = bF, aR0 = bR, aF1 = bF, aR1 = bR;
        #pragma unroll
        for (int k = 0; k < 32; ++k) {
            float f0 = __shfl(sF0, k, 32);
            float r0 = __shfl(sR0, k, 32);
            float f1 = __shfl(sF1, k, 32);
            float r1 = __shfl(sR1, k, 32);
            float hk0 = __shfl(h0, k, 32);
            float hk1 = __shfl(h1, k, 32);
            float wlf = WLF[k][lane], wrf = WRF[k][lane];
            float wlr = WLR[k][lane], wrr = WRR[k][lane];
            aF0 = fmaf(f0, wlf, aF0); aF0 = fmaf(hk0, wrf, aF0);
            aR0 = fmaf(r0, wlr, aR0); aR0 = fmaf(hk0, wrr, aR0);
            aF1 = fmaf(f1, wlf, aF1); aF1 = fmaf(hk1, wrf, aF1);
            aR1 = fmaf(r1, wlr, aR1); aR1 = fmaf(hk1, wrr, aR1);
        }
        hout[n0 * 32 + lane] = fmaxf(aF0, 0.f) + fmaxf(aR0, 0.f);
        hout[n1 * 32 + lane] = fmaxf(aF1, 0.f) + fmaxf(aR1, 0.f);
    }
}

__global__ void k_pair(const float* __restrict__ h, const int* __restrict__ pos1,
                       float* __restrict__ hp, int total) {
    int idx = blockIdx.x * blockDim.x + threadIdx.x;
    int stride = gridDim.x * blockDim.x;
    for (; idx < total; idx += stride) {
        int r = idx >> 5, k = idx & 31;
        int a = pos1[2 * r], b = pos1[2 * r + 1];
        hp[idx] = h[a * 32 + k] * h[b * 32 + k];
    }
}

__global__ void k_final(const float* __restrict__ h, const int* __restrict__ pos2,
                        const float* __restrict__ pw, const float* __restrict__ pb,
                        float* __restrict__ out, int m2) {
    int tid  = threadIdx.x;
    int lane = tid & 31;
    int i    = blockIdx.x * 8 + (tid >> 5);
    if (i >= m2) return;
    int p0 = pos2[2 * i], p1 = pos2[2 * i + 1];
    float v = h[p0 * 32 + lane] * h[p1 * 32 + lane] * pw[lane];
    #pragma unroll
    for (int o = 16; o > 0; o >>= 1) v += __shfl_xor(v, o, 32);
    if (lane == 0) out[i] = v + pb[0];
}

// ---------------- launch ----------------

extern "C" void kernel_launch(void* const* d_in, const int* in_sizes, int n_in,
                              void* d_out, int out_size, void* d_ws, size_t ws_size,
                              hipStream_t stream) {
    const int*   x      = (const int*)d_in[0];
    const int*   edge1  = (const int*)d_in[2];
    const int*   edge2  = (const int*)d_in[3];
    const int*   edge2r = (const int*)d_in[4];
    const int*   pos1   = (const int*)d_in[5];
    const int*   pos2   = (const int*)d_in[6];
    const float* emb    = (const float*)d_in[7];
    const float* gw     = (const float*)d_in[8];
    const float* gb     = (const float*)d_in[9];
    const float* gms    = (const float*)d_in[10];
    const float* c1wl   = (const float*)d_in[11];
    const float* c1bl   = (const float*)d_in[12];
    const float* c1wr   = (const float*)d_in[13];
    const float* c2wl   = (const float*)d_in[14];
    const float* c2bl   = (const float*)d_in[15];
    const float* c2wr   = (const float*)d_in[16];
    const float* c2rwl  = (const float*)d_in[17];
    const float* c2rbl  = (const float*)d_in[18];
    const float* c2rwr  = (const float*)d_in[19];
    const float* pw     = (const float*)d_in[20];
    const float* pb     = (const float*)d_in[21];
    float* out = (float*)d_out;

    char* ws = (char*)d_ws;
    float* hA    = (float*)(ws + OFF_HA);
    float* hB    = (float*)(ws + OFF_HB);
    int*   cnt   = (int*)(ws + OFF_HB);          // overlays hB, dead before k_sage_emb
    int*   csr1  = (int*)(ws + OFF_CSR1);
    int*   csr2  = (int*)(ws + OFF_CSR2);
    int*   csr2r = (int*)(ws + OFF_CSR2R);
    int*   off1  = (int*)(ws + OFF_OFF1);
    int*   off2  = (int*)(ws + OFF_OFF2);
    int*   off2r = (int*)(ws + OFF_OFF2R);
    int*   bsum  = (int*)(ws + OFF_BSUM);
    int*   hist  = (int*)(ws + OFF_HIST);
    float* wlp   = (float*)(ws + OFF_WLP);
    float* wrp   = (float*)(ws + OFF_WRP);
    float* bp    = (float*)(ws + OFF_BP);

    // temp bucketed-edge arrays overlay hA (dead until k_sage layer 2 writes hA)
    int* beF = (int*)(ws + OFF_HA);
    int* beR = (int*)(ws + OFF_HA + 12800000);
    int* be1 = (int*)(ws + OFF_HA);

    hipMemsetAsync(hist, 0, 512, stream);

    // --- GraphNorm stats from x-histogram + layer-1 weight fold ---
    k_histx<<<256, 256, 0, stream>>>(x, hist, NN);
    k_prep<<<1, 256, 0, stream>>>(hist, emb, gw, gb, gms, c1wl, c1bl, c1wr, wlp, wrp, bp);

    // --- CSR build: histogram -> scan -> bin (LDS cursors) -> per-bucket refine ---
    k_hist<<<3 * P_PART, 256, 0, stream>>>(edge2 + E2N, edge2r + E2N, edge1 + E1N, cnt);
    k_scanA<<<SCAN_NB, 256, 0, stream>>>(cnt, bsum);
    k_scanB<<<1, 256, 0, stream>>>(bsum, SCAN_NB);
    k_scanC<<<SCAN_NB, 256, 0, stream>>>(cnt, bsum);
    k_bfillFR<<<2 * P_PART, 256, 0, stream>>>(edge2, edge2 + E2N, edge2r, edge2r + E2N,
                                              cnt, beF, beR);
    k_bcsr2<<<2 * NBKT2, 256, 0, stream>>>(beF, beR, cnt, off2, csr2, off2r, csr2r);
    k_bfill1<<<P_PART, 256, 0, stream>>>(edge1, edge1 + E1N, cnt, be1);
    k_bcsr1<<<NBKT1, 256, 0, stream>>>(be1, cnt, off1, csr1);

    // --- conv1 layer 1: direct from emb via LDS (clobbers cnt region of hB) ---
    k_sage_emb<<<6250, 256, 0, stream>>>(x, emb, hB, csr1, off1, wlp, bp, wrp, NN);

    // --- conv1 layer 2: hB -> hA (clobbers be1/beF temp, now dead) ---
    k_sage<<<2048, 256, 0, stream>>>(hB, hA, csr1, off1,
                                     c1wl + 1024, c1bl + 32, c1wr + 1024, NN);

    // --- pair features: hA (N rows) -> hB (N2 rows; csr1 now dead) ---
    k_pair<<<2048, 256, 0, stream>>>(hA, pos1, hB, N2N * 32);

    // --- conv2: hB -> hA -> hB (fused F+R each layer) ---
    k_sage2<<<2048, 256, 0, stream>>>(hB, hA, csr2, off2, csr2r, off2r,
        c2wl, c2bl, c2wr, c2rwl, c2rbl, c2rwr, N2N);
    k_sage2<<<2048, 256, 0, stream>>>(hA, hB, csr2, off2, csr2r, off2r,
        c2wl + 1024, c2bl + 32, c2wr + 1024, c2rwl + 1024, c2rbl + 32, c2rwr + 1024, N2N);

    // --- head ---
    k_final<<<(MN / 2) / 8, 256, 0, stream>>>(hB, pos2, pw, pb, out, MN / 2);
}

// Round 11
// 870.413 us; speedup vs baseline: 5.2007x; 1.1222x over previous
//
#include <hip/hip_runtime.h>

#define LATENT 32
#define NN     100000
#define E1N    3200000
#define N2N    200000
#define E2N    3200000
#define MN     131072
#define MAXX   100
#define EPSV   1e-5f

#define BK_SH     7          // 128 nodes per bucket
#define PACK_SH   20         // src in bits 0..19, dst_local in bits 20..26
#define PACK_MASK 0xFFFFF
#define NBKT1     782        // ceil(100000/128)
#define NBKT2     1563       // ceil(200000/128)
#define P_PART    128        // partitions per edge list
#define CH        25000      // edges per partition (3.2M / 128)
#define MF_       200064     // NBKT2*128
#define MTOT      500224     // 2*MF_ + NBKT1*128
#define SCAN_NB   245        // ceil(MTOT/2048)

// ---------------- workspace layout (bytes) ----------------
constexpr size_t OFF_HA    = 0;
constexpr size_t OFF_HB    = 25600000;
constexpr size_t OFF_CSR1  = OFF_HB + 12800000;
constexpr size_t OFF_CSR2  = 51200000;
constexpr size_t OFF_CSR2R = 64000000;
constexpr size_t OFF_OFF1  = 76800000;
constexpr size_t OFF_OFF2  = OFF_OFF1 + 400128;
constexpr size_t OFF_OFF2R = OFF_OFF2 + 800128;
constexpr size_t OFF_BSUM  = OFF_OFF2R + 800128;
constexpr size_t OFF_HIST  = OFF_BSUM + 2048;
constexpr size_t OFF_WLP   = OFF_HIST + 512;
constexpr size_t OFF_WRP   = OFF_WLP + 4096;
constexpr size_t OFF_BP    = OFF_WRP + 4096;
constexpr size_t OFF_MARK  = OFF_BP + 256;        // N2N ints (mask for conv2 layer 2)

// ---------------- x histogram + fused GraphNorm/weight prep ----------------

__global__ void k_histx(const int* __restrict__ x, int* __restrict__ hist, int n) {
    __shared__ int h[128];
    int t = threadIdx.x;
    if (t < 128) h[t] = 0;
    __syncthreads();
    int stride = gridDim.x * blockDim.x;
    for (int i = blockIdx.x * blockDim.x + t; i < n; i += stride)
        atomicAdd(&h[x[i]], 1);
    __syncthreads();
    if (t < 128 && h[t] > 0) atomicAdd(&hist[t], h[t]);
}

__global__ void k_prep(const int* __restrict__ hist, const float* __restrict__ emb,
                       const float* __restrict__ gw, const float* __restrict__ gb,
                       const float* __restrict__ gms,
                       const float* __restrict__ wl, const float* __restrict__ bl,
                       const float* __restrict__ wr,
                       float* __restrict__ wlp, float* __restrict__ wrp,
                       float* __restrict__ bp) {
    __shared__ float A[32], B[32];
    int t = threadIdx.x;
    if (t < 32) {
        float m = 0.f, q = 0.f;
        for (int c = 0; c <= MAXX; ++c) {
            float hc = (float)hist[c];
            float v  = emb[c * 32 + t];
            m += hc * v; q += hc * v * v;
        }
        m *= (1.f / (float)NN); q *= (1.f / (float)NN);
        float ms  = gms[t];
        float var = q - 2.f * ms * m * m + ms * ms * m * m;
        float a   = gw[t] / sqrtf(var + EPSV);
        A[t] = a;
        B[t] = gb[t] - a * ms * m;
    }
    __syncthreads();
    for (int i = t; i < 1024; i += 256) {
        int k = i & 31;
        wlp[i] = wl[i] * A[k];
        wrp[i] = wr[i] * A[k];
    }
    if (t < 32) {
        float s = bl[t];
        for (int k = 0; k < 32; ++k) s += (wl[t * 32 + k] + wr[t * 32 + k]) * B[k];
        bp[t] = s;
    }
}

// mark nodes referenced by pos2 (layer-2 of conv2 only needs these)
__global__ void k_mark(const int* __restrict__ pos2, int* __restrict__ mark, int m) {
    int idx = blockIdx.x * blockDim.x + threadIdx.x;
    int stride = gridDim.x * blockDim.x;
    for (; idx < m; idx += stride) mark[pos2[idx]] = 1;
}

// ---------------- partitioned counting-sort CSR build ----------------

__global__ void __launch_bounds__(256) k_hist(const int* __restrict__ dF,
                                              const int* __restrict__ dR,
                                              const int* __restrict__ d1,
                                              int* __restrict__ cnt) {
    __shared__ int hist[NBKT2];
    int t = threadIdx.x;
    int which = blockIdx.x >> 7, p = blockIdx.x & 127;
    const int* d; int nbkt, roff;
    if (which == 0)      { d = dF; nbkt = NBKT2; roff = 0; }
    else if (which == 1) { d = dR; nbkt = NBKT2; roff = MF_; }
    else                 { d = d1; nbkt = NBKT1; roff = 2 * MF_; }
    for (int b = t; b < nbkt; b += 256) hist[b] = 0;
    __syncthreads();
    int e0 = p * CH;
    for (int e = e0 + t; e < e0 + CH; e += 256)
        atomicAdd(&hist[d[e] >> BK_SH], 1);
    __syncthreads();
    for (int b = t; b < nbkt; b += 256) cnt[roff + (b << 7) + p] = hist[b];
}

__global__ void k_scanA(const int* __restrict__ cnt, int* __restrict__ bsum) {
    __shared__ int lds[256];
    int t = threadIdx.x;
    int base = blockIdx.x * 2048 + t * 8;
    int s = 0;
    #pragma unroll
    for (int j = 0; j < 8; ++j) { int e = base + j; if (e < MTOT) s += cnt[e]; }
    lds[t] = s; __syncthreads();
    for (int o = 128; o > 0; o >>= 1) { if (t < o) lds[t] += lds[t + o]; __syncthreads(); }
    if (t == 0) bsum[blockIdx.x] = lds[0];
}

__global__ void k_scanB(int* __restrict__ bsum, int nb) {
    __shared__ int lds[256];
    int t = threadIdx.x;
    int v = (t < nb) ? bsum[t] : 0;
    lds[t] = v; __syncthreads();
    for (int o = 1; o < 256; o <<= 1) {
        int add = (t >= o) ? lds[t - o] : 0;
        __syncthreads();
        lds[t] += add;
        __syncthreads();
    }
    if (t < nb) bsum[t] = lds[t] - v;
}

__global__ void k_scanC(int* __restrict__ cnt, const int* __restrict__ bsum) {
    __shared__ int lds[256];
    int t = threadIdx.x;
    int base = blockIdx.x * 2048 + t * 8;
    int v[8]; int run = 0;
    #pragma unroll
    for (int j = 0; j < 8; ++j) {
        int e = base + j;
        v[j] = (e < MTOT) ? cnt[e] : 0;
        run += v[j];
    }
    int tot = run;
    lds[t] = tot; __syncthreads();
    for (int o = 1; o < 256; o <<= 1) {
        int add = (t >= o) ? lds[t - o] : 0;
        __syncthreads();
        lds[t] += add;
        __syncthreads();
    }
    int ex = lds[t] - tot + bsum[blockIdx.x];
    #pragma unroll
    for (int j = 0; j < 8; ++j) {
        int e = base + j;
        if (e < MTOT) { cnt[e] = ex; ex += v[j]; }
    }
}

__global__ void __launch_bounds__(256) k_bfillFR(
    const int* __restrict__ sF, const int* __restrict__ dF,
    const int* __restrict__ sR, const int* __restrict__ dR,
    const int* __restrict__ cnt, int* __restrict__ beF, int* __restrict__ beR) {
    __shared__ int cur[NBKT2];
    int t = threadIdx.x;
    int which = blockIdx.x >> 7, p = blockIdx.x & 127;
    const int* s; const int* d; int* be; int roff, sub;
    if (which == 0) { s = sF; d = dF; be = beF; roff = 0;   sub = 0; }
    else            { s = sR; d = dR; be = beR; roff = MF_; sub = E2N; }
    for (int b = t; b < NBKT2; b += 256) cur[b] = cnt[roff + (b << 7) + p] - sub;
    __syncthreads();
    int e0 = p * CH;
    for (int e = e0 + t; e < e0 + CH; e += 256) {
        int dd  = d[e];
        int pos = atomicAdd(&cur[dd >> BK_SH], 1);
        be[pos] = s[e] | ((dd & 127) << PACK_SH);
    }
}

__global__ void __launch_bounds__(256) k_bfill1(
    const int* __restrict__ s1, const int* __restrict__ d1,
    const int* __restrict__ cnt, int* __restrict__ be) {
    __shared__ int cur[NBKT1];
    int t = threadIdx.x;
    int p = blockIdx.x;
    for (int b = t; b < NBKT1; b += 256) cur[b] = cnt[2 * MF_ + (b << 7) + p] - 2 * E2N;
    __syncthreads();
    int e0 = p * CH;
    for (int e = e0 + t; e < e0 + CH; e += 256) {
        int dd  = d1[e];
        int pos = atomicAdd(&cur[dd >> BK_SH], 1);
        be[pos] = s1[e] | ((dd & 127) << PACK_SH);
    }
}

// per-bucket: LDS count -> LDS scan -> coalesced off write -> L2-local csr scatter
__device__ __forceinline__ void bcsr_body(const int* __restrict__ bedge,
                                          const int* __restrict__ cnt, int roff, int sub,
                                          int* __restrict__ off, int* __restrict__ csr,
                                          int b, int nbkt, int ntot, int etot) {
    __shared__ int lcnt[128], exs[128], sc[128];
    int t  = threadIdx.x;
    int e0 = cnt[roff + (b << 7)] - sub;
    int e1 = (b + 1 < nbkt) ? cnt[roff + ((b + 1) << 7)] - sub : etot;
    int node0 = b << BK_SH;
    int nloc  = ntot - node0; if (nloc > 128) nloc = 128;
    if (t < 128) lcnt[t] = 0;
    __syncthreads();
    for (int e = e0 + t; e < e1; e += 256)
        atomicAdd(&lcnt[(bedge[e] >> PACK_SH) & 127], 1);
    __syncthreads();
    int cv = (t < 128) ? lcnt[t] : 0;
    if (t < 128) sc[t] = cv;
    __syncthreads();
    for (int o = 1; o < 128; o <<= 1) {
        int add = (t < 128 && t >= o) ? sc[t - o] : 0;
        __syncthreads();
        if (t < 128) sc[t] += add;
        __syncthreads();
    }
    if (t < 128) exs[t] = sc[t] - cv;
    __syncthreads();
    if (t < nloc) off[node0 + t] = e0 + exs[t];
    if (b == nbkt - 1 && t == 0) off[ntot] = e1;
    if (t < 128) lcnt[t] = 0;
    __syncthreads();
    for (int e = e0 + t; e < e1; e += 256) {
        int p   = bedge[e];
        int dl  = (p >> PACK_SH) & 127;
        int pos = e0 + exs[dl] + atomicAdd(&lcnt[dl], 1);
        csr[pos] = p & PACK_MASK;
    }
}

__global__ void __launch_bounds__(256) k_bcsr2(
    const int* beF, const int* beR, const int* __restrict__ cnt,
    int* offF, int* csrF, int* offR, int* csrR) {
    int b = blockIdx.x;
    if (b < NBKT2) bcsr_body(beF, cnt, 0,   0,   offF, csrF, b,         NBKT2, N2N, E2N);
    else           bcsr_body(beR, cnt, MF_, E2N, offR, csrR, b - NBKT2, NBKT2, N2N, E2N);
}

__global__ void __launch_bounds__(256) k_bcsr1(
    const int* be, const int* __restrict__ cnt, int* off, int* csr) {
    bcsr_body(be, cnt, 2 * MF_, 2 * E2N, off, csr, blockIdx.x, NBKT1, NN, E1N);
}

// ---------------- conv1 layer 1: LDS emb table, 4B x-gathers ----------------

__global__ void __launch_bounds__(256) k_sage_emb(
    const int* __restrict__ x, const float* __restrict__ emb,
    float* __restrict__ hout,
    const int* __restrict__ csr, const int* __restrict__ off,
    const float* __restrict__ wlp, const float* __restrict__ bp,
    const float* __restrict__ wrp, int n) {
    __shared__ float embS[(MAXX + 1) * 32];
    __shared__ float wlT[32][33];
    __shared__ float wrT[32][33];
    int tid = threadIdx.x;
    for (int i = tid; i < (MAXX + 1) * 32; i += 256) embS[i] = emb[i];
    for (int i = tid; i < 1024; i += 256) {
        int j = i >> 5, k = i & 31;
        wlT[k][j] = wlp[i];
        wrT[k][j] = wrp[i];
    }
    __syncthreads();
    int lane = tid & 31;
    int g    = blockIdx.x * 8 + (tid >> 5);
    int G    = gridDim.x * 8;
    for (int node = g; node < n; node += G) {
        int s0 = off[node], s1 = off[node + 1];
        float a0 = 0.f, a1 = 0.f, a2 = 0.f, a3 = 0.f;
        for (int base = s0; base < s1; base += 32) {
            int e  = base + lane;
            int xv = x[csr[e < s1 ? e : s1 - 1]];
            int m  = s1 - base; if (m > 32) m = 32;
            for (int j = 0; j < m; j += 4) {
                #pragma unroll
                for (int k = 0; k < 4; ++k) {
                    int jj = j + k;
                    int xj = __shfl(xv, jj & 31, 32);
                    float v = embS[xj * 32 + lane];
                    float w = (jj < m) ? 1.f : 0.f;
                    switch (k) {
                        case 0: a0 = fmaf(v, w, a0); break;
                        case 1: a1 = fmaf(v, w, a1); break;
                        case 2: a2 = fmaf(v, w, a2); break;
                        case 3: a3 = fmaf(v, w, a3); break;
                    }
                }
            }
        }
        int c = s1 - s0;
        float s = ((a0 + a1) + (a2 + a3)) * (1.0f / (float)(c > 0 ? c : 1));
        float hs = embS[x[node] * 32 + lane];
        float acc = bp[lane];
        #pragma unroll
        for (int k = 0; k < 32; ++k) {
            acc = fmaf(__shfl(s, k, 32), wlT[k][lane], acc);
            acc = fmaf(__shfl(hs, k, 32), wrT[k][lane], acc);
        }
        hout[node * 32 + lane] = fmaxf(acc, 0.f);
    }
}

// ---------------- sage kernels ----------------

__device__ __forceinline__ void seg_mean_quad(
    const float* __restrict__ hin,
    const int* __restrict__ cA, int a0, int a1,
    const int* __restrict__ cB, int b0, int b1,
    const int* __restrict__ cC, int c0, int c1,
    const int* __restrict__ cD, int d0, int d1,
    int lane, float& oA, float& oB, float& oC, float& oD)
{
    float aA[4], aB[4], aC[4], aD[4];
    #pragma unroll
    for (int k = 0; k < 4; ++k) { aA[k] = 0.f; aB[k] = 0.f; aC[k] = 0.f; aD[k] = 0.f; }
    int pA = a0, pB = b0, pC = c0, pD = d0;
    while (pA < a1 || pB < b1 || pC < c1 || pD < d1) {
        int iA = 0, iB = 0, iC = 0, iD = 0, mA = 0, mB = 0, mC = 0, mD = 0;
        if (pA < a1) { int e = pA + lane; iA = cA[e < a1 ? e : a1 - 1]; mA = a1 - pA; if (mA > 32) mA = 32; }
        if (pB < b1) { int e = pB + lane; iB = cB[e < b1 ? e : b1 - 1]; mB = b1 - pB; if (mB > 32) mB = 32; }
        if (pC < c1) { int e = pC + lane; iC = cC[e < c1 ? e : c1 - 1]; mC = c1 - pC; if (mC > 32) mC = 32; }
        if (pD < d1) { int e = pD + lane; iD = cD[e < d1 ? e : d1 - 1]; mD = d1 - pD; if (mD > 32) mD = 32; }
        int mm = mA > mB ? mA : mB;
        if (mC > mm) mm = mC;
        if (mD > mm) mm = mD;
        for (int j = 0; j < mm; j += 8) {
            float vA[8], vB[8], vC[8], vD[8];
            bool dA = j < mA, dB = j < mB, dC = j < mC, dD = j < mD;
            if (dA) {
                #pragma unroll
                for (int k = 0; k < 8; ++k)
                    vA[k] = hin[__shfl(iA, (j + k) & 31, 32) * 32 + lane];
            }
            if (dB) {
                #pragma unroll
                for (int k = 0; k < 8; ++k)
                    vB[k] = hin[__shfl(iB, (j + k) & 31, 32) * 32 + lane];
            }
            if (dC) {
                #pragma unroll
                for (int k = 0; k < 8; ++k)
                    vC[k] = hin[__shfl(iC, (j + k) & 31, 32) * 32 + lane];
            }
            if (dD) {
                #pragma unroll
                for (int k = 0; k < 8; ++k)
                    vD[k] = hin[__shfl(iD, (j + k) & 31, 32) * 32 + lane];
            }
            if (dA) {
                #pragma unroll
                for (int k = 0; k < 8; ++k)
                    aA[k & 3] = fmaf(vA[k], (j + k < mA) ? 1.f : 0.f, aA[k & 3]);
            }
            if (dB) {
                #pragma unroll
                for (int k = 0; k < 8; ++k)
                    aB[k & 3] = fmaf(vB[k], (j + k < mB) ? 1.f : 0.f, aB[k & 3]);
            }
            if (dC) {
                #pragma unroll
                for (int k = 0; k < 8; ++k)
                    aC[k & 3] = fmaf(vC[k], (j + k < mC) ? 1.f : 0.f, aC[k & 3]);
            }
            if (dD) {
                #pragma unroll
                for (int k = 0; k < 8; ++k)
                    aD[k & 3] = fmaf(vD[k], (j + k < mD) ? 1.f : 0.f, aD[k & 3]);
            }
        }
        pA += 32; pB += 32; pC += 32; pD += 32;
    }
    int nA = a1 - a0, nB = b1 - b0, nC = c1 - c0, nD = d1 - d0;
    oA = ((aA[0] + aA[1]) + (aA[2] + aA[3])) * (1.0f / (float)(nA > 0 ? nA : 1));
    oB = ((aB[0] + aB[1]) + (aB[2] + aB[3])) * (1.0f / (float)(nB > 0 ? nB : 1));
    oC = ((aC[0] + aC[1]) + (aC[2] + aC[3])) * (1.0f / (float)(nC > 0 ? nC : 1));
    oD = ((aD[0] + aD[1]) + (aD[2] + aD[3])) * (1.0f / (float)(nD > 0 ? nD : 1));
}

__global__ void __launch_bounds__(256) k_sage(
    const float* __restrict__ hin, float* __restrict__ hout,
    const int* __restrict__ csr, const int* __restrict__ off,
    const float* __restrict__ wl, const float* __restrict__ bl, const float* __restrict__ wr,
    int n) {
    __shared__ float wlT[32][33];
    __shared__ float wrT[32][33];
    int tid = threadIdx.x;
    for (int idx = tid; idx < 1024; idx += 256) {
        int j = idx >> 5, k = idx & 31;
        wlT[k][j] = wl[idx];
        wrT[k][j] = wr[idx];
    }
    __syncthreads();
    int lane = tid & 31;
    int g    = blockIdx.x * 8 + (tid >> 5);
    int G    = gridDim.x * 8;
    for (int i = 4 * g; i < n; i += 4 * G) {
        int n0 = i, n1 = i + 1, n2 = i + 2, n3 = i + 3;
        float s0, s1, s2, s3;
        seg_mean_quad(hin, csr, off[n0], off[n0 + 1], csr, off[n1], off[n1 + 1],
                      csr, off[n2], off[n2 + 1], csr, off[n3], off[n3 + 1],
                      lane, s0, s1, s2, s3);
        float h0 = hin[n0 * 32 + lane];
        float h1 = hin[n1 * 32 + lane];
        float h2 = hin[n2 * 32 + lane];
        float h3 = hin[n3 * 32 + lane];
        float bb = bl[lane];
        float A0 = bb, A1 = bb, A2 = bb, A3 = bb;
        #pragma unroll
        for (int k = 0; k < 32; ++k) {
            float wlk = wlT[k][lane], wrk = wrT[k][lane];
            A0 = fmaf(__shfl(s0, k, 32), wlk, A0);
            A0 = fmaf(__shfl(h0, k, 32), wrk, A0);
            A1 = fmaf(__shfl(s1, k, 32), wlk, A1);
            A1 = fmaf(__shfl(h1, k, 32), wrk, A1);
            A2 = fmaf(__shfl(s2, k, 32), wlk, A2);
            A2 = fmaf(__shfl(h2, k, 32), wrk, A2);
            A3 = fmaf(__shfl(s3, k, 32), wlk, A3);
            A3 = fmaf(__shfl(h3, k, 32), wrk, A3);
        }
        hout[n0 * 32 + lane] = fmaxf(A0, 0.f);
        hout[n1 * 32 + lane] = fmaxf(A1, 0.f);
        hout[n2 * 32 + lane] = fmaxf(A2, 0.f);
        hout[n3 * 32 + lane] = fmaxf(A3, 0.f);
    }
}

// fused dual-direction sage; optional per-node mask (mask==nullptr -> all)
__global__ void __launch_bounds__(256) k_sage2(
    const float* __restrict__ hin, float* __restrict__ hout,
    const int* __restrict__ csrF, const int* __restrict__ offF,
    const int* __restrict__ csrR, const int* __restrict__ offR,
    const float* __restrict__ wlF, const float* __restrict__ blF, const float* __restrict__ wrF,
    const float* __restrict__ wlR, const float* __restrict__ blR, const float* __restrict__ wrR,
    const int* __restrict__ mask, int n) {
    __shared__ float WLF[32][33], WRF[32][33], WLR[32][33], WRR[32][33];
    int tid = threadIdx.x;
    for (int idx = tid; idx < 1024; idx += 256) {
        int j = idx >> 5, k = idx & 31;
        WLF[k][j] = wlF[idx];
        WRF[k][j] = wrF[idx];
        WLR[k][j] = wlR[idx];
        WRR[k][j] = wrR[idx];
    }
    __syncthreads();
    int lane = tid & 31;
    int g    = blockIdx.x * 8 + (tid >> 5);
    int G    = gridDim.x * 8;
    for (int i = 2 * g; i < n; i += 2 * G) {
        int n0 = i, n1 = i + 1;
        int m0 = mask ? mask[n0] : 1;
        int m1 = mask ? mask[n1] : 1;
        if (!(m0 | m1)) continue;
        int f00 = offF[n0], f01 = offF[n0 + 1], r00 = offR[n0], r01 = offR[n0 + 1];
        int f10 = offF[n1], f11 = offF[n1 + 1], r10 = offR[n1], r11 = offR[n1 + 1];
        if (!m0) { f01 = f00; r01 = r00; }
        if (!m1) { f11 = f10; r11 = r10; }
        float sF0, sR0, sF1, sR1;
        seg_mean_quad(hin, csrF, f00, f01, csrR, r00, r01,
                      csrF, f10, f11, csrR, r10, r11, lane, sF0, sR0, sF1, sR1);
        float bF = blF[lane], bR = blR[lane];
        if (m0) {
            float h0 = hin[n0 * 32 + lane];
            float aF0 = bF, aR0 = bR;
            #pragma unroll
            for (int k = 0; k < 32; ++k) {
                float f0 = __shfl(sF0, k, 32);
                float r0 = __shfl(sR0, k, 32);
                float hk0 = __shfl(h0, k, 32);
                aF0 = fmaf(f0, WLF[k][lane], aF0);
                aF0 = fmaf(hk0, WRF[k][lane], aF0);
                aR0 = fmaf(r0, WLR[k][lane], aR0);
                aR0 = fmaf(hk0, WRR[k][lane], aR0);
            }
            hout[n0 * 32 + lane] = fmaxf(aF0, 0.f) + fmaxf(aR0, 0.f);
        }
        if (m1) {
            float h1 = hin[n1 * 32 + lane];
            float aF1 = bF, aR1 = bR;
            #pragma unroll
            for (int k = 0; k < 32; ++k) {
                float f1 = __shfl(sF1, k, 32);
                float r1 = __shfl(sR1, k, 32);
                float hk1 = __shfl(h1, k, 32);
                aF1 = fmaf(f1, WLF[k][lane], aF1);
                aF1 = fmaf(hk1, WRF[k][lane], aF1);
                aR1 = fmaf(r1, WLR[k][lane], aR1);
                aR1 = fmaf(hk1, WRR[k][lane], aR1);
            }
            hout[n1 * 32 + lane] = fmaxf(aF1, 0.f) + fmaxf(aR1, 0.f);
        }
    }
}

__global__ void k_pair(const float* __restrict__ h, const int* __restrict__ pos1,
                       float* __restrict__ hp, int total) {
    int idx = blockIdx.x * blockDim.x + threadIdx.x;
    int stride = gridDim.x * blockDim.x;
    for (; idx < total; idx += stride) {
        int r = idx >> 5, k = idx & 31;
        int a = pos1[2 * r], b = pos1[2 * r + 1];
        hp[idx] = h[a * 32 + k] * h[b * 32 + k];
    }
}

__global__ void k_final(const float* __restrict__ h, const int* __restrict__ pos2,
                        const float* __restrict__ pw, const float* __restrict__ pb,
                        float* __restrict__ out, int m2) {
    int tid  = threadIdx.x;
    int lane = tid & 31;
    int i    = blockIdx.x * 8 + (tid >> 5);
    if (i >= m2) return;
    int p0 = pos2[2 * i], p1 = pos2[2 * i + 1];
    float v = h[p0 * 32 + lane] * h[p1 * 32 + lane] * pw[lane];
    #pragma unroll
    for (int o = 16; o > 0; o >>= 1) v += __shfl_xor(v, o, 32);
    if (lane == 0) out[i] = v + pb[0];
}

// ---------------- launch ----------------

extern "C" void kernel_launch(void* const* d_in, const int* in_sizes, int n_in,
                              void* d_out, int out_size, void* d_ws, size_t ws_size,
                              hipStream_t stream) {
    const int*   x      = (const int*)d_in[0];
    const int*   edge1  = (const int*)d_in[2];
    const int*   edge2  = (const int*)d_in[3];
    const int*   edge2r = (const int*)d_in[4];
    const int*   pos1   = (const int*)d_in[5];
    const int*   pos2   = (const int*)d_in[6];
    const float* emb    = (const float*)d_in[7];
    const float* gw     = (const float*)d_in[8];
    const float* gb     = (const float*)d_in[9];
    const float* gms    = (const float*)d_in[10];
    const float* c1wl   = (const float*)d_in[11];
    const float* c1bl   = (const float*)d_in[12];
    const float* c1wr   = (const float*)d_in[13];
    const float* c2wl   = (const float*)d_in[14];
    const float* c2bl   = (const float*)d_in[15];
    const float* c2wr   = (const float*)d_in[16];
    const float* c2rwl  = (const float*)d_in[17];
    const float* c2rbl  = (const float*)d_in[18];
    const float* c2rwr  = (const float*)d_in[19];
    const float* pw     = (const float*)d_in[20];
    const float* pb     = (const float*)d_in[21];
    float* out = (float*)d_out;

    char* ws = (char*)d_ws;
    float* hA    = (float*)(ws + OFF_HA);
    float* hB    = (float*)(ws + OFF_HB);
    int*   cnt   = (int*)(ws + OFF_HB);          // overlays hB, dead before k_sage_emb
    int*   csr1  = (int*)(ws + OFF_CSR1);
    int*   csr2  = (int*)(ws + OFF_CSR2);
    int*   csr2r = (int*)(ws + OFF_CSR2R);
    int*   off1  = (int*)(ws + OFF_OFF1);
    int*   off2  = (int*)(ws + OFF_OFF2);
    int*   off2r = (int*)(ws + OFF_OFF2R);
    int*   bsum  = (int*)(ws + OFF_BSUM);
    int*   hist  = (int*)(ws + OFF_HIST);
    float* wlp   = (float*)(ws + OFF_WLP);
    float* wrp   = (float*)(ws + OFF_WRP);
    float* bp    = (float*)(ws + OFF_BP);
    int*   mark  = (int*)(ws + OFF_MARK);

    // temp bucketed-edge arrays overlay hA (dead until k_sage layer 2 writes hA)
    int* beF = (int*)(ws + OFF_HA);
    int* beR = (int*)(ws + OFF_HA + 12800000);
    int* be1 = (int*)(ws + OFF_HA);

    hipMemsetAsync(hist, 0, 512, stream);
    hipMemsetAsync(mark, 0, N2N * sizeof(int), stream);

    // --- GraphNorm stats from x-histogram + layer-1 weight fold; pos2 mark ---
    k_histx<<<256, 256, 0, stream>>>(x, hist, NN);
    k_prep<<<1, 256, 0, stream>>>(hist, emb, gw, gb, gms, c1wl, c1bl, c1wr, wlp, wrp, bp);
    k_mark<<<256, 256, 0, stream>>>(pos2, mark, MN);

    // --- CSR build: histogram -> scan -> bin (LDS cursors) -> per-bucket refine ---
    k_hist<<<3 * P_PART, 256, 0, stream>>>(edge2 + E2N, edge2r + E2N, edge1 + E1N, cnt);
    k_scanA<<<SCAN_NB, 256, 0, stream>>>(cnt, bsum);
    k_scanB<<<1, 256, 0, stream>>>(bsum, SCAN_NB);
    k_scanC<<<SCAN_NB, 256, 0, stream>>>(cnt, bsum);
    k_bfillFR<<<2 * P_PART, 256, 0, stream>>>(edge2, edge2 + E2N, edge2r, edge2r + E2N,
                                              cnt, beF, beR);
    k_bcsr2<<<2 * NBKT2, 256, 0, stream>>>(beF, beR, cnt, off2, csr2, off2r, csr2r);
    k_bfill1<<<P_PART, 256, 0, stream>>>(edge1, edge1 + E1N, cnt, be1);
    k_bcsr1<<<NBKT1, 256, 0, stream>>>(be1, cnt, off1, csr1);

    // --- conv1 layer 1: direct from emb via LDS (clobbers cnt region of hB) ---
    k_sage_emb<<<6250, 256, 0, stream>>>(x, emb, hB, csr1, off1, wlp, bp, wrp, NN);

    // --- conv1 layer 2: hB -> hA (clobbers be1/beF temp, now dead) ---
    k_sage<<<2048, 256, 0, stream>>>(hB, hA, csr1, off1,
                                     c1wl + 1024, c1bl + 32, c1wr + 1024, NN);

    // --- pair features: hA (N rows) -> hB (N2 rows; csr1 now dead) ---
    k_pair<<<2048, 256, 0, stream>>>(hA, pos1, hB, N2N * 32);

    // --- conv2 layer 1 (all nodes): hB -> hA ---
    k_sage2<<<2048, 256, 0, stream>>>(hB, hA, csr2, off2, csr2r, off2r,
        c2wl, c2bl, c2wr, c2rwl, c2rbl, c2rwr, (const int*)nullptr, N2N);

    // --- conv2 layer 2 (only pos2-referenced nodes): hA -> hB ---
    k_sage2<<<2048, 256, 0, stream>>>(hA, hB, csr2, off2, csr2r, off2r,
        c2wl + 1024, c2bl + 32, c2wr + 1024, c2rwl + 1024, c2rbl + 32, c2rwr + 1024,
        mark, N2N);

    // --- head ---
    k_final<<<(MN / 2) / 8, 256, 0, stream>>>(hB, pos2, pw, pb, out, MN / 2);
}

// Round 12
// 858.157 us; speedup vs baseline: 5.2749x; 1.0143x over previous
//
#include <hip/hip_runtime.h>
#include <hip/hip_fp16.h>

#define LATENT 32
#define NN     100000
#define E1N    3200000
#define N2N    200000
#define E2N    3200000
#define MN     131072
#define MAXX   100
#define EPSV   1e-5f

#define BK_SH     7          // 128 nodes per bucket
#define PACK_SH   20         // src in bits 0..19, dst_local in bits 20..26
#define PACK_MASK 0xFFFFF
#define NBKT1     782        // ceil(100000/128)
#define NBKT2     1563       // ceil(200000/128)
#define P_PART    128        // partitions per edge list
#define CH        25000      // edges per partition (3.2M / 128)
#define MF_       200064     // NBKT2*128
#define MTOT      500224     // 2*MF_ + NBKT1*128
#define SCAN_NB   245        // ceil(MTOT/2048)

// ---------------- workspace layout (bytes) ----------------
// h tables are fp16 now (12.8MB for N2N, 6.4MB for NN)
constexpr size_t OFF_HA    = 0;                   // 25.6MB region (be temps / hA fp16)
constexpr size_t OFF_HB    = 25600000;            // 25.6MB region (cnt / h1 / hB fp16)
constexpr size_t OFF_CSR1  = OFF_HB + 12800000;
constexpr size_t OFF_CSR2  = 51200000;
constexpr size_t OFF_CSR2R = 64000000;
constexpr size_t OFF_OFF1  = 76800000;
constexpr size_t OFF_OFF2  = OFF_OFF1 + 400128;
constexpr size_t OFF_OFF2R = OFF_OFF2 + 800128;
constexpr size_t OFF_BSUM  = OFF_OFF2R + 800128;
constexpr size_t OFF_HIST  = OFF_BSUM + 2048;
constexpr size_t OFF_WLP   = OFF_HIST + 512;
constexpr size_t OFF_WRP   = OFF_WLP + 4096;
constexpr size_t OFF_BP    = OFF_WRP + 4096;
constexpr size_t OFF_MARK  = OFF_BP + 256;        // N2N ints

// ---------------- x histogram + fused GraphNorm/weight prep ----------------

__global__ void k_histx(const int* __restrict__ x, int* __restrict__ hist, int n) {
    __shared__ int h[128];
    int t = threadIdx.x;
    if (t < 128) h[t] = 0;
    __syncthreads();
    int stride = gridDim.x * blockDim.x;
    for (int i = blockIdx.x * blockDim.x + t; i < n; i += stride)
        atomicAdd(&h[x[i]], 1);
    __syncthreads();
    if (t < 128 && h[t] > 0) atomicAdd(&hist[t], h[t]);
}

__global__ void k_prep(const int* __restrict__ hist, const float* __restrict__ emb,
                       const float* __restrict__ gw, const float* __restrict__ gb,
                       const float* __restrict__ gms,
                       const float* __restrict__ wl, const float* __restrict__ bl,
                       const float* __restrict__ wr,
                       float* __restrict__ wlp, float* __restrict__ wrp,
                       float* __restrict__ bp) {
    __shared__ float A[32], B[32];
    int t = threadIdx.x;
    if (t < 32) {
        float m = 0.f, q = 0.f;
        for (int c = 0; c <= MAXX; ++c) {
            float hc = (float)hist[c];
            float v  = emb[c * 32 + t];
            m += hc * v; q += hc * v * v;
        }
        m *= (1.f / (float)NN); q *= (1.f / (float)NN);
        float ms  = gms[t];
        float var = q - 2.f * ms * m * m + ms * ms * m * m;
        float a   = gw[t] / sqrtf(var + EPSV);
        A[t] = a;
        B[t] = gb[t] - a * ms * m;
    }
    __syncthreads();
    for (int i = t; i < 1024; i += 256) {
        int k = i & 31;
        wlp[i] = wl[i] * A[k];
        wrp[i] = wr[i] * A[k];
    }
    if (t < 32) {
        float s = bl[t];
        for (int k = 0; k < 32; ++k) s += (wl[t * 32 + k] + wr[t * 32 + k]) * B[k];
        bp[t] = s;
    }
}

// mark nodes referenced by pos2 (layer-2 of conv2 only needs these)
__global__ void k_mark(const int* __restrict__ pos2, int* __restrict__ mark, int m) {
    int idx = blockIdx.x * blockDim.x + threadIdx.x;
    int stride = gridDim.x * blockDim.x;
    for (; idx < m; idx += stride) mark[pos2[idx]] = 1;
}

// ---------------- partitioned counting-sort CSR build ----------------

__global__ void __launch_bounds__(256) k_hist(const int* __restrict__ dF,
                                              const int* __restrict__ dR,
                                              const int* __restrict__ d1,
                                              int* __restrict__ cnt) {
    __shared__ int hist[NBKT2];
    int t = threadIdx.x;
    int which = blockIdx.x >> 7, p = blockIdx.x & 127;
    const int* d; int nbkt, roff;
    if (which == 0)      { d = dF; nbkt = NBKT2; roff = 0; }
    else if (which == 1) { d = dR; nbkt = NBKT2; roff = MF_; }
    else                 { d = d1; nbkt = NBKT1; roff = 2 * MF_; }
    for (int b = t; b < nbkt; b += 256) hist[b] = 0;
    __syncthreads();
    int e0 = p * CH;
    for (int e = e0 + t; e < e0 + CH; e += 256)
        atomicAdd(&hist[d[e] >> BK_SH], 1);
    __syncthreads();
    for (int b = t; b < nbkt; b += 256) cnt[roff + (b << 7) + p] = hist[b];
}

__global__ void k_scanA(const int* __restrict__ cnt, int* __restrict__ bsum) {
    __shared__ int lds[256];
    int t = threadIdx.x;
    int base = blockIdx.x * 2048 + t * 8;
    int s = 0;
    #pragma unroll
    for (int j = 0; j < 8; ++j) { int e = base + j; if (e < MTOT) s += cnt[e]; }
    lds[t] = s; __syncthreads();
    for (int o = 128; o > 0; o >>= 1) { if (t < o) lds[t] += lds[t + o]; __syncthreads(); }
    if (t == 0) bsum[blockIdx.x] = lds[0];
}

__global__ void k_scanB(int* __restrict__ bsum, int nb) {
    __shared__ int lds[256];
    int t = threadIdx.x;
    int v = (t < nb) ? bsum[t] : 0;
    lds[t] = v; __syncthreads();
    for (int o = 1; o < 256; o <<= 1) {
        int add = (t >= o) ? lds[t - o] : 0;
        __syncthreads();
        lds[t] += add;
        __syncthreads();
    }
    if (t < nb) bsum[t] = lds[t] - v;
}

__global__ void k_scanC(int* __restrict__ cnt, const int* __restrict__ bsum) {
    __shared__ int lds[256];
    int t = threadIdx.x;
    int base = blockIdx.x * 2048 + t * 8;
    int v[8]; int run = 0;
    #pragma unroll
    for (int j = 0; j < 8; ++j) {
        int e = base + j;
        v[j] = (e < MTOT) ? cnt[e] : 0;
        run += v[j];
    }
    int tot = run;
    lds[t] = tot; __syncthreads();
    for (int o = 1; o < 256; o <<= 1) {
        int add = (t >= o) ? lds[t - o] : 0;
        __syncthreads();
        lds[t] += add;
        __syncthreads();
    }
    int ex = lds[t] - tot + bsum[blockIdx.x];
    #pragma unroll
    for (int j = 0; j < 8; ++j) {
        int e = base + j;
        if (e < MTOT) { cnt[e] = ex; ex += v[j]; }
    }
}

__global__ void __launch_bounds__(256) k_bfillFR(
    const int* __restrict__ sF, const int* __restrict__ dF,
    const int* __restrict__ sR, const int* __restrict__ dR,
    const int* __restrict__ cnt, int* __restrict__ beF, int* __restrict__ beR) {
    __shared__ int cur[NBKT2];
    int t = threadIdx.x;
    int which = blockIdx.x >> 7, p = blockIdx.x & 127;
    const int* s; const int* d; int* be; int roff, sub;
    if (which == 0) { s = sF; d = dF; be = beF; roff = 0;   sub = 0; }
    else            { s = sR; d = dR; be = beR; roff = MF_; sub = E2N; }
    for (int b = t; b < NBKT2; b += 256) cur[b] = cnt[roff + (b << 7) + p] - sub;
    __syncthreads();
    int e0 = p * CH;
    for (int e = e0 + t; e < e0 + CH; e += 256) {
        int dd  = d[e];
        int pos = atomicAdd(&cur[dd >> BK_SH], 1);
        be[pos] = s[e] | ((dd & 127) << PACK_SH);
    }
}

__global__ void __launch_bounds__(256) k_bfill1(
    const int* __restrict__ s1, const int* __restrict__ d1,
    const int* __restrict__ cnt, int* __restrict__ be) {
    __shared__ int cur[NBKT1];
    int t = threadIdx.x;
    int p = blockIdx.x;
    for (int b = t; b < NBKT1; b += 256) cur[b] = cnt[2 * MF_ + (b << 7) + p] - 2 * E2N;
    __syncthreads();
    int e0 = p * CH;
    for (int e = e0 + t; e < e0 + CH; e += 256) {
        int dd  = d1[e];
        int pos = atomicAdd(&cur[dd >> BK_SH], 1);
        be[pos] = s1[e] | ((dd & 127) << PACK_SH);
    }
}

// per-bucket: LDS count -> LDS scan -> coalesced off write -> L2-local csr scatter
__device__ __forceinline__ void bcsr_body(const int* __restrict__ bedge,
                                          const int* __restrict__ cnt, int roff, int sub,
                                          int* __restrict__ off, int* __restrict__ csr,
                                          int b, int nbkt, int ntot, int etot) {
    __shared__ int lcnt[128], exs[128], sc[128];
    int t  = threadIdx.x;
    int e0 = cnt[roff + (b << 7)] - sub;
    int e1 = (b + 1 < nbkt) ? cnt[roff + ((b + 1) << 7)] - sub : etot;
    int node0 = b << BK_SH;
    int nloc  = ntot - node0; if (nloc > 128) nloc = 128;
    if (t < 128) lcnt[t] = 0;
    __syncthreads();
    for (int e = e0 + t; e < e1; e += 256)
        atomicAdd(&lcnt[(bedge[e] >> PACK_SH) & 127], 1);
    __syncthreads();
    int cv = (t < 128) ? lcnt[t] : 0;
    if (t < 128) sc[t] = cv;
    __syncthreads();
    for (int o = 1; o < 128; o <<= 1) {
        int add = (t < 128 && t >= o) ? sc[t - o] : 0;
        __syncthreads();
        if (t < 128) sc[t] += add;
        __syncthreads();
    }
    if (t < 128) exs[t] = sc[t] - cv;
    __syncthreads();
    if (t < nloc) off[node0 + t] = e0 + exs[t];
    if (b == nbkt - 1 && t == 0) off[ntot] = e1;
    if (t < 128) lcnt[t] = 0;
    __syncthreads();
    for (int e = e0 + t; e < e1; e += 256) {
        int p   = bedge[e];
        int dl  = (p >> PACK_SH) & 127;
        int pos = e0 + exs[dl] + atomicAdd(&lcnt[dl], 1);
        csr[pos] = p & PACK_MASK;
    }
}

__global__ void __launch_bounds__(256) k_bcsr2(
    const int* beF, const int* beR, const int* __restrict__ cnt,
    int* offF, int* csrF, int* offR, int* csrR) {
    int b = blockIdx.x;
    if (b < NBKT2) bcsr_body(beF, cnt, 0,   0,   offF, csrF, b,         NBKT2, N2N, E2N);
    else           bcsr_body(beR, cnt, MF_, E2N, offR, csrR, b - NBKT2, NBKT2, N2N, E2N);
}

__global__ void __launch_bounds__(256) k_bcsr1(
    const int* be, const int* __restrict__ cnt, int* off, int* csr) {
    bcsr_body(be, cnt, 2 * MF_, 2 * E2N, off, csr, blockIdx.x, NBKT1, NN, E1N);
}

// ---------------- conv1 layer 1: LDS emb table, 4B x-gathers, fp16 out ----------------

__global__ void __launch_bounds__(256) k_sage_emb(
    const int* __restrict__ x, const float* __restrict__ emb,
    __half* __restrict__ hout,
    const int* __restrict__ csr, const int* __restrict__ off,
    const float* __restrict__ wlp, const float* __restrict__ bp,
    const float* __restrict__ wrp, int n) {
    __shared__ float embS[(MAXX + 1) * 32];
    __shared__ float wlT[32][33];
    __shared__ float wrT[32][33];
    int tid = threadIdx.x;
    for (int i = tid; i < (MAXX + 1) * 32; i += 256) embS[i] = emb[i];
    for (int i = tid; i < 1024; i += 256) {
        int j = i >> 5, k = i & 31;
        wlT[k][j] = wlp[i];
        wrT[k][j] = wrp[i];
    }
    __syncthreads();
    int lane = tid & 31;
    int g    = blockIdx.x * 8 + (tid >> 5);
    int G    = gridDim.x * 8;
    for (int node = g; node < n; node += G) {
        int s0 = off[node], s1 = off[node + 1];
        float a0 = 0.f, a1 = 0.f, a2 = 0.f, a3 = 0.f;
        for (int base = s0; base < s1; base += 32) {
            int e  = base + lane;
            int xv = x[csr[e < s1 ? e : s1 - 1]];
            int m  = s1 - base; if (m > 32) m = 32;
            for (int j = 0; j < m; j += 4) {
                #pragma unroll
                for (int k = 0; k < 4; ++k) {
                    int jj = j + k;
                    int xj = __shfl(xv, jj & 31, 32);
                    float v = embS[xj * 32 + lane];
                    float w = (jj < m) ? 1.f : 0.f;
                    switch (k) {
                        case 0: a0 = fmaf(v, w, a0); break;
                        case 1: a1 = fmaf(v, w, a1); break;
                        case 2: a2 = fmaf(v, w, a2); break;
                        case 3: a3 = fmaf(v, w, a3); break;
                    }
                }
            }
        }
        int c = s1 - s0;
        float s = ((a0 + a1) + (a2 + a3)) * (1.0f / (float)(c > 0 ? c : 1));
        float hs = embS[x[node] * 32 + lane];
        float acc = bp[lane];
        #pragma unroll
        for (int k = 0; k < 32; ++k) {
            acc = fmaf(__shfl(s, k, 32), wlT[k][lane], acc);
            acc = fmaf(__shfl(hs, k, 32), wrT[k][lane], acc);
        }
        hout[node * 32 + lane] = __float2half(fmaxf(acc, 0.f));
    }
}

// ---------------- sage kernels (fp16 h tables, fp32 math) ----------------

__device__ __forceinline__ void seg_mean_quad(
    const __half* __restrict__ hin,
    const int* __restrict__ cA, int a0, int a1,
    const int* __restrict__ cB, int b0, int b1,
    const int* __restrict__ cC, int c0, int c1,
    const int* __restrict__ cD, int d0, int d1,
    int lane, float& oA, float& oB, float& oC, float& oD)
{
    float aA[4], aB[4], aC[4], aD[4];
    #pragma unroll
    for (int k = 0; k < 4; ++k) { aA[k] = 0.f; aB[k] = 0.f; aC[k] = 0.f; aD[k] = 0.f; }
    int pA = a0, pB = b0, pC = c0, pD = d0;
    while (pA < a1 || pB < b1 || pC < c1 || pD < d1) {
        int iA = 0, iB = 0, iC = 0, iD = 0, mA = 0, mB = 0, mC = 0, mD = 0;
        if (pA < a1) { int e = pA + lane; iA = cA[e < a1 ? e : a1 - 1]; mA = a1 - pA; if (mA > 32) mA = 32; }
        if (pB < b1) { int e = pB + lane; iB = cB[e < b1 ? e : b1 - 1]; mB = b1 - pB; if (mB > 32) mB = 32; }
        if (pC < c1) { int e = pC + lane; iC = cC[e < c1 ? e : c1 - 1]; mC = c1 - pC; if (mC > 32) mC = 32; }
        if (pD < d1) { int e = pD + lane; iD = cD[e < d1 ? e : d1 - 1]; mD = d1 - pD; if (mD > 32) mD = 32; }
        int mm = mA > mB ? mA : mB;
        if (mC > mm) mm = mC;
        if (mD > mm) mm = mD;
        for (int j = 0; j < mm; j += 8) {
            __half vA[8], vB[8], vC[8], vD[8];
            bool dA = j < mA, dB = j < mB, dC = j < mC, dD = j < mD;
            if (dA) {
                #pragma unroll
                for (int k = 0; k < 8; ++k)
                    vA[k] = hin[__shfl(iA, (j + k) & 31, 32) * 32 + lane];
            }
            if (dB) {
                #pragma unroll
                for (int k = 0; k < 8; ++k)
                    vB[k] = hin[__shfl(iB, (j + k) & 31, 32) * 32 + lane];
            }
            if (dC) {
                #pragma unroll
                for (int k = 0; k < 8; ++k)
                    vC[k] = hin[__shfl(iC, (j + k) & 31, 32) * 32 + lane];
            }
            if (dD) {
                #pragma unroll
                for (int k = 0; k < 8; ++k)
                    vD[k] = hin[__shfl(iD, (j + k) & 31, 32) * 32 + lane];
            }
            if (dA) {
                #pragma unroll
                for (int k = 0; k < 8; ++k)
                    aA[k & 3] = fmaf(__half2float(vA[k]), (j + k < mA) ? 1.f : 0.f, aA[k & 3]);
            }
            if (dB) {
                #pragma unroll
                for (int k = 0; k < 8; ++k)
                    aB[k & 3] = fmaf(__half2float(vB[k]), (j + k < mB) ? 1.f : 0.f, aB[k & 3]);
            }
            if (dC) {
                #pragma unroll
                for (int k = 0; k < 8; ++k)
                    aC[k & 3] = fmaf(__half2float(vC[k]), (j + k < mC) ? 1.f : 0.f, aC[k & 3]);
            }
            if (dD) {
                #pragma unroll
                for (int k = 0; k < 8; ++k)
                    aD[k & 3] = fmaf(__half2float(vD[k]), (j + k < mD) ? 1.f : 0.f, aD[k & 3]);
            }
        }
        pA += 32; pB += 32; pC += 32; pD += 32;
    }
    int nA = a1 - a0, nB = b1 - b0, nC = c1 - c0, nD = d1 - d0;
    oA = ((aA[0] + aA[1]) + (aA[2] + aA[3])) * (1.0f / (float)(nA > 0 ? nA : 1));
    oB = ((aB[0] + aB[1]) + (aB[2] + aB[3])) * (1.0f / (float)(nB > 0 ? nB : 1));
    oC = ((aC[0] + aC[1]) + (aC[2] + aC[3])) * (1.0f / (float)(nC > 0 ? nC : 1));
    oD = ((aD[0] + aD[1]) + (aD[2] + aD[3])) * (1.0f / (float)(nD > 0 ? nD : 1));
}

__global__ void __launch_bounds__(256) k_sage(
    const __half* __restrict__ hin, __half* __restrict__ hout,
    const int* __restrict__ csr, const int* __restrict__ off,
    const float* __restrict__ wl, const float* __restrict__ bl, const float* __restrict__ wr,
    int n) {
    __shared__ float wlT[32][33];
    __shared__ float wrT[32][33];
    int tid = threadIdx.x;
    for (int idx = tid; idx < 1024; idx += 256) {
        int j = idx >> 5, k = idx & 31;
        wlT[k][j] = wl[idx];
        wrT[k][j] = wr[idx];
    }
    __syncthreads();
    int lane = tid & 31;
    int g    = blockIdx.x * 8 + (tid >> 5);
    int G    = gridDim.x * 8;
    for (int i = 4 * g; i < n; i += 4 * G) {
        int n0 = i, n1 = i + 1, n2 = i + 2, n3 = i + 3;
        float s0, s1, s2, s3;
        seg_mean_quad(hin, csr, off[n0], off[n0 + 1], csr, off[n1], off[n1 + 1],
                      csr, off[n2], off[n2 + 1], csr, off[n3], off[n3 + 1],
                      lane, s0, s1, s2, s3);
        float h0 = __half2float(hin[n0 * 32 + lane]);
        float h1 = __half2float(hin[n1 * 32 + lane]);
        float h2 = __half2float(hin[n2 * 32 + lane]);
        float h3 = __half2float(hin[n3 * 32 + lane]);
        float bb = bl[lane];
        float A0 = bb, A1 = bb, A2 = bb, A3 = bb;
        #pragma unroll
        for (int k = 0; k < 32; ++k) {
            float wlk = wlT[k][lane], wrk = wrT[k][lane];
            A0 = fmaf(__shfl(s0, k, 32), wlk, A0);
            A0 = fmaf(__shfl(h0, k, 32), wrk, A0);
            A1 = fmaf(__shfl(s1, k, 32), wlk, A1);
            A1 = fmaf(__shfl(h1, k, 32), wrk, A1);
            A2 = fmaf(__shfl(s2, k, 32), wlk, A2);
            A2 = fmaf(__shfl(h2, k, 32), wrk, A2);
            A3 = fmaf(__shfl(s3, k, 32), wlk, A3);
            A3 = fmaf(__shfl(h3, k, 32), wrk, A3);
        }
        hout[n0 * 32 + lane] = __float2half(fmaxf(A0, 0.f));
        hout[n1 * 32 + lane] = __float2half(fmaxf(A1, 0.f));
        hout[n2 * 32 + lane] = __float2half(fmaxf(A2, 0.f));
        hout[n3 * 32 + lane] = __float2half(fmaxf(A3, 0.f));
    }
}

// fused dual-direction sage; optional per-node mask (mask==nullptr -> all)
__global__ void __launch_bounds__(256) k_sage2(
    const __half* __restrict__ hin, __half* __restrict__ hout,
    const int* __restrict__ csrF, const int* __restrict__ offF,
    const int* __restrict__ csrR, const int* __restrict__ offR,
    const float* __restrict__ wlF, const float* __restrict__ blF, const float* __restrict__ wrF,
    const float* __restrict__ wlR, const float* __restrict__ blR, const float* __restrict__ wrR,
    const int* __restrict__ mask, int n) {
    __shared__ float WLF[32][33], WRF[32][33], WLR[32][33], WRR[32][33];
    int tid = threadIdx.x;
    for (int idx = tid; idx < 1024; idx += 256) {
        int j = idx >> 5, k = idx & 31;
        WLF[k][j] = wlF[idx];
        WRF[k][j] = wrF[idx];
        WLR[k][j] = wlR[idx];
        WRR[k][j] = wrR[idx];
    }
    __syncthreads();
    int lane = tid & 31;
    int g    = blockIdx.x * 8 + (tid >> 5);
    int G    = gridDim.x * 8;
    for (int i = 2 * g; i < n; i += 2 * G) {
        int n0 = i, n1 = i + 1;
        int m0 = mask ? mask[n0] : 1;
        int m1 = mask ? mask[n1] : 1;
        if (!(m0 | m1)) continue;
        int f00 = offF[n0], f01 = offF[n0 + 1], r00 = offR[n0], r01 = offR[n0 + 1];
        int f10 = offF[n1], f11 = offF[n1 + 1], r10 = offR[n1], r11 = offR[n1 + 1];
        if (!m0) { f01 = f00; r01 = r00; }
        if (!m1) { f11 = f10; r11 = r10; }
        float sF0, sR0, sF1, sR1;
        seg_mean_quad(hin, csrF, f00, f01, csrR, r00, r01,
                      csrF, f10, f11, csrR, r10, r11, lane, sF0, sR0, sF1, sR1);
        float bF = blF[lane], bR = blR[lane];
        if (m0) {
            float h0 = __half2float(hin[n0 * 32 + lane]);
            float aF0 = bF, aR0 = bR;
            #pragma unroll
            for (int k = 0; k < 32; ++k) {
                float f0 = __shfl(sF0, k, 32);
                float r0 = __shfl(sR0, k, 32);
                float hk0 = __shfl(h0, k, 32);
                aF0 = fmaf(f0, WLF[k][lane], aF0);
                aF0 = fmaf(hk0, WRF[k][lane], aF0);
                aR0 = fmaf(r0, WLR[k][lane], aR0);
                aR0 = fmaf(hk0, WRR[k][lane], aR0);
            }
            hout[n0 * 32 + lane] = __float2half(fmaxf(aF0, 0.f) + fmaxf(aR0, 0.f));
        }
        if (m1) {
            float h1 = __half2float(hin[n1 * 32 + lane]);
            float aF1 = bF, aR1 = bR;
            #pragma unroll
            for (int k = 0; k < 32; ++k) {
                float f1 = __shfl(sF1, k, 32);
                float r1 = __shfl(sR1, k, 32);
                float hk1 = __shfl(h1, k, 32);
                aF1 = fmaf(f1, WLF[k][lane], aF1);
                aF1 = fmaf(hk1, WRF[k][lane], aF1);
                aR1 = fmaf(r1, WLR[k][lane], aR1);
                aR1 = fmaf(hk1, WRR[k][lane], aR1);
            }
            hout[n1 * 32 + lane] = __float2half(fmaxf(aF1, 0.f) + fmaxf(aR1, 0.f));
        }
    }
}

__global__ void k_pair(const __half* __restrict__ h, const int* __restrict__ pos1,
                       __half* __restrict__ hp, int total) {
    int idx = blockIdx.x * blockDim.x + threadIdx.x;
    int stride = gridDim.x * blockDim.x;
    for (; idx < total; idx += stride) {
        int r = idx >> 5, k = idx & 31;
        int a = pos1[2 * r], b = pos1[2 * r + 1];
        hp[idx] = __float2half(__half2float(h[a * 32 + k]) * __half2float(h[b * 32 + k]));
    }
}

__global__ void k_final(const __half* __restrict__ h, const int* __restrict__ pos2,
                        const float* __restrict__ pw, const float* __restrict__ pb,
                        float* __restrict__ out, int m2) {
    int tid  = threadIdx.x;
    int lane = tid & 31;
    int i    = blockIdx.x * 8 + (tid >> 5);
    if (i >= m2) return;
    int p0 = pos2[2 * i], p1 = pos2[2 * i + 1];
    float v = __half2float(h[p0 * 32 + lane]) * __half2float(h[p1 * 32 + lane]) * pw[lane];
    #pragma unroll
    for (int o = 16; o > 0; o >>= 1) v += __shfl_xor(v, o, 32);
    if (lane == 0) out[i] = v + pb[0];
}

// ---------------- launch ----------------

extern "C" void kernel_launch(void* const* d_in, const int* in_sizes, int n_in,
                              void* d_out, int out_size, void* d_ws, size_t ws_size,
                              hipStream_t stream) {
    const int*   x      = (const int*)d_in[0];
    const int*   edge1  = (const int*)d_in[2];
    const int*   edge2  = (const int*)d_in[3];
    const int*   edge2r = (const int*)d_in[4];
    const int*   pos1   = (const int*)d_in[5];
    const int*   pos2   = (const int*)d_in[6];
    const float* emb    = (const float*)d_in[7];
    const float* gw     = (const float*)d_in[8];
    const float* gb     = (const float*)d_in[9];
    const float* gms    = (const float*)d_in[10];
    const float* c1wl   = (const float*)d_in[11];
    const float* c1bl   = (const float*)d_in[12];
    const float* c1wr   = (const float*)d_in[13];
    const float* c2wl   = (const float*)d_in[14];
    const float* c2bl   = (const float*)d_in[15];
    const float* c2wr   = (const float*)d_in[16];
    const float* c2rwl  = (const float*)d_in[17];
    const float* c2rbl  = (const float*)d_in[18];
    const float* c2rwr  = (const float*)d_in[19];
    const float* pw     = (const float*)d_in[20];
    const float* pb     = (const float*)d_in[21];
    float* out = (float*)d_out;

    char* ws = (char*)d_ws;
    __half* hA   = (__half*)(ws + OFF_HA);
    __half* hB   = (__half*)(ws + OFF_HB);
    int*   cnt   = (int*)(ws + OFF_HB);          // overlays hB, dead before k_sage_emb
    int*   csr1  = (int*)(ws + OFF_CSR1);
    int*   csr2  = (int*)(ws + OFF_CSR2);
    int*   csr2r = (int*)(ws + OFF_CSR2R);
    int*   off1  = (int*)(ws + OFF_OFF1);
    int*   off2  = (int*)(ws + OFF_OFF2);
    int*   off2r = (int*)(ws + OFF_OFF2R);
    int*   bsum  = (int*)(ws + OFF_BSUM);
    int*   hist  = (int*)(ws + OFF_HIST);
    float* wlp   = (float*)(ws + OFF_WLP);
    float* wrp   = (float*)(ws + OFF_WRP);
    float* bp    = (float*)(ws + OFF_BP);
    int*   mark  = (int*)(ws + OFF_MARK);

    // temp bucketed-edge arrays overlay hA (dead until k_sage writes hA)
    int* beF = (int*)(ws + OFF_HA);
    int* beR = (int*)(ws + OFF_HA + 12800000);
    int* be1 = (int*)(ws + OFF_HA);

    hipMemsetAsync(hist, 0, 512, stream);
    hipMemsetAsync(mark, 0, N2N * sizeof(int), stream);

    // --- GraphNorm stats from x-histogram + layer-1 weight fold; pos2 mark ---
    k_histx<<<256, 256, 0, stream>>>(x, hist, NN);
    k_prep<<<1, 256, 0, stream>>>(hist, emb, gw, gb, gms, c1wl, c1bl, c1wr, wlp, wrp, bp);
    k_mark<<<256, 256, 0, stream>>>(pos2, mark, MN);

    // --- CSR build: histogram -> scan -> bin (LDS cursors) -> per-bucket refine ---
    k_hist<<<3 * P_PART, 256, 0, stream>>>(edge2 + E2N, edge2r + E2N, edge1 + E1N, cnt);
    k_scanA<<<SCAN_NB, 256, 0, stream>>>(cnt, bsum);
    k_scanB<<<1, 256, 0, stream>>>(bsum, SCAN_NB);
    k_scanC<<<SCAN_NB, 256, 0, stream>>>(cnt, bsum);
    k_bfillFR<<<2 * P_PART, 256, 0, stream>>>(edge2, edge2 + E2N, edge2r, edge2r + E2N,
                                              cnt, beF, beR);
    k_bcsr2<<<2 * NBKT2, 256, 0, stream>>>(beF, beR, cnt, off2, csr2, off2r, csr2r);
    k_bfill1<<<P_PART, 256, 0, stream>>>(edge1, edge1 + E1N, cnt, be1);
    k_bcsr1<<<NBKT1, 256, 0, stream>>>(be1, cnt, off1, csr1);

    // --- conv1 layer 1: direct from emb via LDS -> h1 fp16 (clobbers cnt) ---
    k_sage_emb<<<6250, 256, 0, stream>>>(x, emb, hB, csr1, off1, wlp, bp, wrp, NN);

    // --- conv1 layer 2: hB -> hA fp16 (clobbers be temp, now dead) ---
    k_sage<<<2048, 256, 0, stream>>>(hB, hA, csr1, off1,
                                     c1wl + 1024, c1bl + 32, c1wr + 1024, NN);

    // --- pair features: hA (N rows) -> hB (N2 rows fp16; csr1 now dead) ---
    k_pair<<<2048, 256, 0, stream>>>(hA, pos1, hB, N2N * 32);

    // --- conv2 layer 1 (all nodes): hB -> hA ---
    k_sage2<<<2048, 256, 0, stream>>>(hB, hA, csr2, off2, csr2r, off2r,
        c2wl, c2bl, c2wr, c2rwl, c2rbl, c2rwr, (const int*)nullptr, N2N);

    // --- conv2 layer 2 (only pos2-referenced nodes): hA -> hB ---
    k_sage2<<<2048, 256, 0, stream>>>(hA, hB, csr2, off2, csr2r, off2r,
        c2wl + 1024, c2bl + 32, c2wr + 1024, c2rwl + 1024, c2rbl + 32, c2rwr + 1024,
        mark, N2N);

    // --- head ---
    k_final<<<(MN / 2) / 8, 256, 0, stream>>>(hB, pos2, pw, pb, out, MN / 2);
}

// Round 13
// 805.232 us; speedup vs baseline: 5.6216x; 1.0657x over previous
//
#include <hip/hip_runtime.h>
#include <hip/hip_fp16.h>

#define LATENT 32
#define NN     100000
#define E1N    3200000
#define N2N    200000
#define E2N    3200000
#define MN     131072
#define MAXX   100
#define EPSV   1e-5f

#define BK_SH     7          // 128 nodes per bucket
#define PACK_SH   20         // src in bits 0..19, dst_local in bits 20..26
#define PACK_MASK 0xFFFFF
#define NBKT1     782        // ceil(100000/128)
#define NBKT2     1563       // ceil(200000/128)
#define P_PART    128        // partitions per edge list
#define CH        25000      // edges per partition (3.2M / 128)
#define MF_       200064     // NBKT2*128
#define MTOT      500224     // 2*MF_ + NBKT1*128
#define SCAN_NB   245        // ceil(MTOT/2048)

// ---------------- workspace layout (bytes) ----------------
constexpr size_t OFF_HA    = 0;                   // 25.6MB region (be temps / hA fp16)
constexpr size_t OFF_HB    = 25600000;            // 25.6MB region (cnt / h1 / hB fp16)
constexpr size_t OFF_CSR1  = OFF_HB + 12800000;
constexpr size_t OFF_CSR2  = 51200000;
constexpr size_t OFF_CSR2R = 64000000;
constexpr size_t OFF_OFF1  = 76800000;
constexpr size_t OFF_OFF2  = OFF_OFF1 + 400128;
constexpr size_t OFF_OFF2R = OFF_OFF2 + 800128;
constexpr size_t OFF_BSUM  = OFF_OFF2R + 800128;
constexpr size_t OFF_HIST  = OFF_BSUM + 2048;
constexpr size_t OFF_WLP   = OFF_HIST + 512;
constexpr size_t OFF_WRP   = OFF_WLP + 4096;
constexpr size_t OFF_BP    = OFF_WRP + 4096;
constexpr size_t OFF_MARK  = OFF_BP + 256;        // N2N ints

// ---------------- x histogram + fused GraphNorm/weight prep ----------------

__global__ void k_histx(const int* __restrict__ x, int* __restrict__ hist, int n) {
    __shared__ int h[128];
    int t = threadIdx.x;
    if (t < 128) h[t] = 0;
    __syncthreads();
    int stride = gridDim.x * blockDim.x;
    for (int i = blockIdx.x * blockDim.x + t; i < n; i += stride)
        atomicAdd(&h[x[i]], 1);
    __syncthreads();
    if (t < 128 && h[t] > 0) atomicAdd(&hist[t], h[t]);
}

__global__ void k_prep(const int* __restrict__ hist, const float* __restrict__ emb,
                       const float* __restrict__ gw, const float* __restrict__ gb,
                       const float* __restrict__ gms,
                       const float* __restrict__ wl, const float* __restrict__ bl,
                       const float* __restrict__ wr,
                       float* __restrict__ wlp, float* __restrict__ wrp,
                       float* __restrict__ bp) {
    __shared__ float A[32], B[32];
    int t = threadIdx.x;
    if (t < 32) {
        float m = 0.f, q = 0.f;
        for (int c = 0; c <= MAXX; ++c) {
            float hc = (float)hist[c];
            float v  = emb[c * 32 + t];
            m += hc * v; q += hc * v * v;
        }
        m *= (1.f / (float)NN); q *= (1.f / (float)NN);
        float ms  = gms[t];
        float var = q - 2.f * ms * m * m + ms * ms * m * m;
        float a   = gw[t] / sqrtf(var + EPSV);
        A[t] = a;
        B[t] = gb[t] - a * ms * m;
    }
    __syncthreads();
    for (int i = t; i < 1024; i += 256) {
        int k = i & 31;
        wlp[i] = wl[i] * A[k];
        wrp[i] = wr[i] * A[k];
    }
    if (t < 32) {
        float s = bl[t];
        for (int k = 0; k < 32; ++k) s += (wl[t * 32 + k] + wr[t * 32 + k]) * B[k];
        bp[t] = s;
    }
}

__global__ void k_mark(const int* __restrict__ pos2, int* __restrict__ mark, int m) {
    int idx = blockIdx.x * blockDim.x + threadIdx.x;
    int stride = gridDim.x * blockDim.x;
    for (; idx < m; idx += stride) mark[pos2[idx]] = 1;
}

// ---------------- partitioned counting-sort CSR build ----------------

__global__ void __launch_bounds__(256) k_hist(const int* __restrict__ dF,
                                              const int* __restrict__ dR,
                                              const int* __restrict__ d1,
                                              int* __restrict__ cnt) {
    __shared__ int hist[NBKT2];
    int t = threadIdx.x;
    int which = blockIdx.x >> 7, p = blockIdx.x & 127;
    const int* d; int nbkt, roff;
    if (which == 0)      { d = dF; nbkt = NBKT2; roff = 0; }
    else if (which == 1) { d = dR; nbkt = NBKT2; roff = MF_; }
    else                 { d = d1; nbkt = NBKT1; roff = 2 * MF_; }
    for (int b = t; b < nbkt; b += 256) hist[b] = 0;
    __syncthreads();
    int e0 = p * CH;
    for (int e = e0 + t; e < e0 + CH; e += 256)
        atomicAdd(&hist[d[e] >> BK_SH], 1);
    __syncthreads();
    for (int b = t; b < nbkt; b += 256) cnt[roff + (b << 7) + p] = hist[b];
}

__global__ void k_scanA(const int* __restrict__ cnt, int* __restrict__ bsum) {
    __shared__ int lds[256];
    int t = threadIdx.x;
    int base = blockIdx.x * 2048 + t * 8;
    int s = 0;
    #pragma unroll
    for (int j = 0; j < 8; ++j) { int e = base + j; if (e < MTOT) s += cnt[e]; }
    lds[t] = s; __syncthreads();
    for (int o = 128; o > 0; o >>= 1) { if (t < o) lds[t] += lds[t + o]; __syncthreads(); }
    if (t == 0) bsum[blockIdx.x] = lds[0];
}

__global__ void k_scanB(int* __restrict__ bsum, int nb) {
    __shared__ int lds[256];
    int t = threadIdx.x;
    int v = (t < nb) ? bsum[t] : 0;
    lds[t] = v; __syncthreads();
    for (int o = 1; o < 256; o <<= 1) {
        int add = (t >= o) ? lds[t - o] : 0;
        __syncthreads();
        lds[t] += add;
        __syncthreads();
    }
    if (t < nb) bsum[t] = lds[t] - v;
}

__global__ void k_scanC(int* __restrict__ cnt, const int* __restrict__ bsum) {
    __shared__ int lds[256];
    int t = threadIdx.x;
    int base = blockIdx.x * 2048 + t * 8;
    int v[8]; int run = 0;
    #pragma unroll
    for (int j = 0; j < 8; ++j) {
        int e = base + j;
        v[j] = (e < MTOT) ? cnt[e] : 0;
        run += v[j];
    }
    int tot = run;
    lds[t] = tot; __syncthreads();
    for (int o = 1; o < 256; o <<= 1) {
        int add = (t >= o) ? lds[t - o] : 0;
        __syncthreads();
        lds[t] += add;
        __syncthreads();
    }
    int ex = lds[t] - tot + bsum[blockIdx.x];
    #pragma unroll
    for (int j = 0; j < 8; ++j) {
        int e = base + j;
        if (e < MTOT) { cnt[e] = ex; ex += v[j]; }
    }
}

__global__ void __launch_bounds__(256) k_bfillFR(
    const int* __restrict__ sF, const int* __restrict__ dF,
    const int* __restrict__ sR, const int* __restrict__ dR,
    const int* __restrict__ cnt, int* __restrict__ beF, int* __restrict__ beR) {
    __shared__ int cur[NBKT2];
    int t = threadIdx.x;
    int which = blockIdx.x >> 7, p = blockIdx.x & 127;
    const int* s; const int* d; int* be; int roff, sub;
    if (which == 0) { s = sF; d = dF; be = beF; roff = 0;   sub = 0; }
    else            { s = sR; d = dR; be = beR; roff = MF_; sub = E2N; }
    for (int b = t; b < NBKT2; b += 256) cur[b] = cnt[roff + (b << 7) + p] - sub;
    __syncthreads();
    int e0 = p * CH;
    for (int e = e0 + t; e < e0 + CH; e += 256) {
        int dd  = d[e];
        int pos = atomicAdd(&cur[dd >> BK_SH], 1);
        be[pos] = s[e] | ((dd & 127) << PACK_SH);
    }
}

__global__ void __launch_bounds__(256) k_bfill1(
    const int* __restrict__ s1, const int* __restrict__ d1,
    const int* __restrict__ cnt, int* __restrict__ be) {
    __shared__ int cur[NBKT1];
    int t = threadIdx.x;
    int p = blockIdx.x;
    for (int b = t; b < NBKT1; b += 256) cur[b] = cnt[2 * MF_ + (b << 7) + p] - 2 * E2N;
    __syncthreads();
    int e0 = p * CH;
    for (int e = e0 + t; e < e0 + CH; e += 256) {
        int dd  = d1[e];
        int pos = atomicAdd(&cur[dd >> BK_SH], 1);
        be[pos] = s1[e] | ((dd & 127) << PACK_SH);
    }
}

__device__ __forceinline__ void bcsr_body(const int* __restrict__ bedge,
                                          const int* __restrict__ cnt, int roff, int sub,
                                          int* __restrict__ off, int* __restrict__ csr,
                                          int b, int nbkt, int ntot, int etot) {
    __shared__ int lcnt[128], exs[128], sc[128];
    int t  = threadIdx.x;
    int e0 = cnt[roff + (b << 7)] - sub;
    int e1 = (b + 1 < nbkt) ? cnt[roff + ((b + 1) << 7)] - sub : etot;
    int node0 = b << BK_SH;
    int nloc  = ntot - node0; if (nloc > 128) nloc = 128;
    if (t < 128) lcnt[t] = 0;
    __syncthreads();
    for (int e = e0 + t; e < e1; e += 256)
        atomicAdd(&lcnt[(bedge[e] >> PACK_SH) & 127], 1);
    __syncthreads();
    int cv = (t < 128) ? lcnt[t] : 0;
    if (t < 128) sc[t] = cv;
    __syncthreads();
    for (int o = 1; o < 128; o <<= 1) {
        int add = (t < 128 && t >= o) ? sc[t - o] : 0;
        __syncthreads();
        if (t < 128) sc[t] += add;
        __syncthreads();
    }
    if (t < 128) exs[t] = sc[t] - cv;
    __syncthreads();
    if (t < nloc) off[node0 + t] = e0 + exs[t];
    if (b == nbkt - 1 && t == 0) off[ntot] = e1;
    if (t < 128) lcnt[t] = 0;
    __syncthreads();
    for (int e = e0 + t; e < e1; e += 256) {
        int p   = bedge[e];
        int dl  = (p >> PACK_SH) & 127;
        int pos = e0 + exs[dl] + atomicAdd(&lcnt[dl], 1);
        csr[pos] = p & PACK_MASK;
    }
}

__global__ void __launch_bounds__(256) k_bcsr2(
    const int* beF, const int* beR, const int* __restrict__ cnt,
    int* offF, int* csrF, int* offR, int* csrR) {
    int b = blockIdx.x;
    if (b < NBKT2) bcsr_body(beF, cnt, 0,   0,   offF, csrF, b,         NBKT2, N2N, E2N);
    else           bcsr_body(beR, cnt, MF_, E2N, offR, csrR, b - NBKT2, NBKT2, N2N, E2N);
}

__global__ void __launch_bounds__(256) k_bcsr1(
    const int* be, const int* __restrict__ cnt, int* off, int* csr) {
    bcsr_body(be, cnt, 2 * MF_, 2 * E2N, off, csr, blockIdx.x, NBKT1, NN, E1N);
}

// ---------------- conv1 layer 1: LDS emb table, 4B x-gathers, fp16 out ----------------

__global__ void __launch_bounds__(256) k_sage_emb(
    const int* __restrict__ x, const float* __restrict__ emb,
    __half* __restrict__ hout,
    const int* __restrict__ csr, const int* __restrict__ off,
    const float* __restrict__ wlp, const float* __restrict__ bp,
    const float* __restrict__ wrp, int n) {
    __shared__ float embS[(MAXX + 1) * 32];
    __shared__ float wlT[32][33];
    __shared__ float wrT[32][33];
    int tid = threadIdx.x;
    for (int i = tid; i < (MAXX + 1) * 32; i += 256) embS[i] = emb[i];
    for (int i = tid; i < 1024; i += 256) {
        int j = i >> 5, k = i & 31;
        wlT[k][j] = wlp[i];
        wrT[k][j] = wrp[i];
    }
    __syncthreads();
    int lane = tid & 31;
    int g    = blockIdx.x * 8 + (tid >> 5);
    int G    = gridDim.x * 8;
    for (int node = g; node < n; node += G) {
        int s0 = off[node], s1 = off[node + 1];
        float a0 = 0.f, a1 = 0.f, a2 = 0.f, a3 = 0.f;
        for (int base = s0; base < s1; base += 32) {
            int e  = base + lane;
            int xv = x[csr[e < s1 ? e : s1 - 1]];
            int m  = s1 - base; if (m > 32) m = 32;
            for (int j = 0; j < m; j += 4) {
                #pragma unroll
                for (int k = 0; k < 4; ++k) {
                    int jj = j + k;
                    int xj = __shfl(xv, jj & 31, 32);
                    float v = embS[xj * 32 + lane];
                    float w = (jj < m) ? 1.f : 0.f;
                    switch (k) {
                        case 0: a0 = fmaf(v, w, a0); break;
                        case 1: a1 = fmaf(v, w, a1); break;
                        case 2: a2 = fmaf(v, w, a2); break;
                        case 3: a3 = fmaf(v, w, a3); break;
                    }
                }
            }
        }
        int c = s1 - s0;
        float s = ((a0 + a1) + (a2 + a3)) * (1.0f / (float)(c > 0 ? c : 1));
        float hs = embS[x[node] * 32 + lane];
        float acc = bp[lane];
        #pragma unroll
        for (int k = 0; k < 32; ++k) {
            acc = fmaf(__shfl(s, k, 32), wlT[k][lane], acc);
            acc = fmaf(__shfl(hs, k, 32), wrT[k][lane], acc);
        }
        hout[node * 32 + lane] = __float2half(fmaxf(acc, 0.f));
    }
}

// ---------------- dual-edge fp16 segment mean: 2 edges per gather instr ----------------
// lanes 0-15 process even edges, 16-31 odd edges; each lane loads __half2 (4B).
// Returns per-stream (sE, sO): lane l holds features 2*(l&15) [E] and 2*(l&15)+1 [O].

__device__ __forceinline__ void seg4_h2(
    const __half2* __restrict__ h2,
    const int* __restrict__ cA, int a0, int a1,
    const int* __restrict__ cB, int b0, int b1,
    const int* __restrict__ cC, int c0, int c1,
    const int* __restrict__ cD, int d0, int d1,
    int lane,
    float& oEA, float& oOA, float& oEB, float& oOB,
    float& oEC, float& oOC, float& oED, float& oOD)
{
    float eA[2] = {0.f, 0.f}, oA[2] = {0.f, 0.f};
    float eB[2] = {0.f, 0.f}, oB[2] = {0.f, 0.f};
    float eC[2] = {0.f, 0.f}, oC[2] = {0.f, 0.f};
    float eD[2] = {0.f, 0.f}, oD[2] = {0.f, 0.f};
    int hsel = (lane >> 4) & 1;
    int col  = lane & 15;
    int pA = a0, pB = b0, pC = c0, pD = d0;
    while (pA < a1 || pB < b1 || pC < c1 || pD < d1) {
        int iA = 0, iB = 0, iC = 0, iD = 0, mA = 0, mB = 0, mC = 0, mD = 0;
        if (pA < a1) { int e = pA + lane; iA = cA[e < a1 ? e : a1 - 1]; mA = a1 - pA; if (mA > 32) mA = 32; }
        if (pB < b1) { int e = pB + lane; iB = cB[e < b1 ? e : b1 - 1]; mB = b1 - pB; if (mB > 32) mB = 32; }
        if (pC < c1) { int e = pC + lane; iC = cC[e < c1 ? e : c1 - 1]; mC = c1 - pC; if (mC > 32) mC = 32; }
        if (pD < d1) { int e = pD + lane; iD = cD[e < d1 ? e : d1 - 1]; mD = d1 - pD; if (mD > 32) mD = 32; }
        int mm = mA > mB ? mA : mB;
        if (mC > mm) mm = mC;
        if (mD > mm) mm = mD;
        for (int j = 0; j < mm; j += 16) {
            __half2 vA[8], vB[8], vC[8], vD[8];
            bool dA = j < mA, dB = j < mB, dC = j < mC, dD = j < mD;
            if (dA) {
                #pragma unroll
                for (int kk = 0; kk < 8; ++kk) {
                    int es = j + 2 * kk + hsel;
                    vA[kk] = h2[__shfl(iA, es & 31, 32) * 16 + col];
                }
            }
            if (dB) {
                #pragma unroll
                for (int kk = 0; kk < 8; ++kk) {
                    int es = j + 2 * kk + hsel;
                    vB[kk] = h2[__shfl(iB, es & 31, 32) * 16 + col];
                }
            }
            if (dC) {
                #pragma unroll
                for (int kk = 0; kk < 8; ++kk) {
                    int es = j + 2 * kk + hsel;
                    vC[kk] = h2[__shfl(iC, es & 31, 32) * 16 + col];
                }
            }
            if (dD) {
                #pragma unroll
                for (int kk = 0; kk < 8; ++kk) {
                    int es = j + 2 * kk + hsel;
                    vD[kk] = h2[__shfl(iD, es & 31, 32) * 16 + col];
                }
            }
            if (dA) {
                #pragma unroll
                for (int kk = 0; kk < 8; ++kk) {
                    int es = j + 2 * kk + hsel;
                    float w = (es < mA) ? 1.f : 0.f;
                    float2 f = __half22float2(vA[kk]);
                    eA[kk & 1] = fmaf(f.x, w, eA[kk & 1]);
                    oA[kk & 1] = fmaf(f.y, w, oA[kk & 1]);
                }
            }
            if (dB) {
                #pragma unroll
                for (int kk = 0; kk < 8; ++kk) {
                    int es = j + 2 * kk + hsel;
                    float w = (es < mB) ? 1.f : 0.f;
                    float2 f = __half22float2(vB[kk]);
                    eB[kk & 1] = fmaf(f.x, w, eB[kk & 1]);
                    oB[kk & 1] = fmaf(f.y, w, oB[kk & 1]);
                }
            }
            if (dC) {
                #pragma unroll
                for (int kk = 0; kk < 8; ++kk) {
                    int es = j + 2 * kk + hsel;
                    float w = (es < mC) ? 1.f : 0.f;
                    float2 f = __half22float2(vC[kk]);
                    eC[kk & 1] = fmaf(f.x, w, eC[kk & 1]);
                    oC[kk & 1] = fmaf(f.y, w, oC[kk & 1]);
                }
            }
            if (dD) {
                #pragma unroll
                for (int kk = 0; kk < 8; ++kk) {
                    int es = j + 2 * kk + hsel;
                    float w = (es < mD) ? 1.f : 0.f;
                    float2 f = __half22float2(vD[kk]);
                    eD[kk & 1] = fmaf(f.x, w, eD[kk & 1]);
                    oD[kk & 1] = fmaf(f.y, w, oD[kk & 1]);
                }
            }
        }
        pA += 32; pB += 32; pC += 32; pD += 32;
    }
    float sE, sO;
    int nA = a1 - a0; float vA_ = 1.f / (float)(nA > 0 ? nA : 1);
    sE = eA[0] + eA[1]; sE += __shfl_xor(sE, 16, 32);
    sO = oA[0] + oA[1]; sO += __shfl_xor(sO, 16, 32);
    oEA = sE * vA_; oOA = sO * vA_;
    int nB = b1 - b0; float vB_ = 1.f / (float)(nB > 0 ? nB : 1);
    sE = eB[0] + eB[1]; sE += __shfl_xor(sE, 16, 32);
    sO = oB[0] + oB[1]; sO += __shfl_xor(sO, 16, 32);
    oEB = sE * vB_; oOB = sO * vB_;
    int nC = c1 - c0; float vC_ = 1.f / (float)(nC > 0 ? nC : 1);
    sE = eC[0] + eC[1]; sE += __shfl_xor(sE, 16, 32);
    sO = oC[0] + oC[1]; sO += __shfl_xor(sO, 16, 32);
    oEC = sE * vC_; oOC = sO * vC_;
    int nD = d1 - d0; float vD_ = 1.f / (float)(nD > 0 ? nD : 1);
    sE = eD[0] + eD[1]; sE += __shfl_xor(sE, 16, 32);
    sO = oD[0] + oD[1]; sO += __shfl_xor(sO, 16, 32);
    oED = sE * vD_; oOD = sO * vD_;
}

// ---------------- sage kernels (fp16 tables, dual-edge gathers) ----------------

__global__ void __launch_bounds__(256) k_sage(
    const __half* __restrict__ hin, __half* __restrict__ hout,
    const int* __restrict__ csr, const int* __restrict__ off,
    const float* __restrict__ wl, const float* __restrict__ bl, const float* __restrict__ wr,
    int n) {
    __shared__ float wlT[32][33];
    __shared__ float wrT[32][33];
    int tid = threadIdx.x;
    for (int idx = tid; idx < 1024; idx += 256) {
        int j = idx >> 5, k = idx & 31;
        wlT[k][j] = wl[idx];
        wrT[k][j] = wr[idx];
    }
    __syncthreads();
    const __half2* h2 = (const __half2*)hin;
    int lane = tid & 31;
    int g    = blockIdx.x * 8 + (tid >> 5);
    int G    = gridDim.x * 8;
    for (int i = 4 * g; i < n; i += 4 * G) {
        int n0 = i, n1 = i + 1, n2 = i + 2, n3 = i + 3;
        float sE0, sO0, sE1, sO1, sE2, sO2, sE3, sO3;
        seg4_h2(h2, csr, off[n0], off[n0 + 1], csr, off[n1], off[n1 + 1],
                csr, off[n2], off[n2 + 1], csr, off[n3], off[n3 + 1],
                lane, sE0, sO0, sE1, sO1, sE2, sO2, sE3, sO3);
        float h0 = __half2float(hin[n0 * 32 + lane]);
        float h1 = __half2float(hin[n1 * 32 + lane]);
        float h2f = __half2float(hin[n2 * 32 + lane]);
        float h3 = __half2float(hin[n3 * 32 + lane]);
        float bb = bl[lane];
        float A0 = bb, A1 = bb, A2 = bb, A3 = bb;
        #pragma unroll
        for (int k = 0; k < 32; ++k) {
            float wlk = wlT[k][lane], wrk = wrT[k][lane];
            float s0k = __shfl((k & 1) ? sO0 : sE0, k >> 1, 32);
            float s1k = __shfl((k & 1) ? sO1 : sE1, k >> 1, 32);
            float s2k = __shfl((k & 1) ? sO2 : sE2, k >> 1, 32);
            float s3k = __shfl((k & 1) ? sO3 : sE3, k >> 1, 32);
            A0 = fmaf(s0k, wlk, A0);
            A0 = fmaf(__shfl(h0, k, 32), wrk, A0);
            A1 = fmaf(s1k, wlk, A1);
            A1 = fmaf(__shfl(h1, k, 32), wrk, A1);
            A2 = fmaf(s2k, wlk, A2);
            A2 = fmaf(__shfl(h2f, k, 32), wrk, A2);
            A3 = fmaf(s3k, wlk, A3);
            A3 = fmaf(__shfl(h3, k, 32), wrk, A3);
        }
        hout[n0 * 32 + lane] = __float2half(fmaxf(A0, 0.f));
        hout[n1 * 32 + lane] = __float2half(fmaxf(A1, 0.f));
        hout[n2 * 32 + lane] = __float2half(fmaxf(A2, 0.f));
        hout[n3 * 32 + lane] = __float2half(fmaxf(A3, 0.f));
    }
}

// fused dual-direction sage; optional per-node mask (mask==nullptr -> all)
__global__ void __launch_bounds__(256) k_sage2(
    const __half* __restrict__ hin, __half* __restrict__ hout,
    const int* __restrict__ csrF, const int* __restrict__ offF,
    const int* __restrict__ csrR, const int* __restrict__ offR,
    const float* __restrict__ wlF, const float* __restrict__ blF, const float* __restrict__ wrF,
    const float* __restrict__ wlR, const float* __restrict__ blR, const float* __restrict__ wrR,
    const int* __restrict__ mask, int n) {
    __shared__ float WLF[32][33], WRF[32][33], WLR[32][33], WRR[32][33];
    int tid = threadIdx.x;
    for (int idx = tid; idx < 1024; idx += 256) {
        int j = idx >> 5, k = idx & 31;
        WLF[k][j] = wlF[idx];
        WRF[k][j] = wrF[idx];
        WLR[k][j] = wlR[idx];
        WRR[k][j] = wrR[idx];
    }
    __syncthreads();
    const __half2* h2 = (const __half2*)hin;
    int lane = tid & 31;
    int g    = blockIdx.x * 8 + (tid >> 5);
    int G    = gridDim.x * 8;
    for (int i = 2 * g; i < n; i += 2 * G) {
        int n0 = i, n1 = i + 1;
        int m0 = mask ? mask[n0] : 1;
        int m1 = mask ? mask[n1] : 1;
        if (!(m0 | m1)) continue;
        int f00 = offF[n0], f01 = offF[n0 + 1], r00 = offR[n0], r01 = offR[n0 + 1];
        int f10 = offF[n1], f11 = offF[n1 + 1], r10 = offR[n1], r11 = offR[n1 + 1];
        if (!m0) { f01 = f00; r01 = r00; }
        if (!m1) { f11 = f10; r11 = r10; }
        float sEF0, sOF0, sER0, sOR0, sEF1, sOF1, sER1, sOR1;
        seg4_h2(h2, csrF, f00, f01, csrR, r00, r01,
                csrF, f10, f11, csrR, r10, r11,
                lane, sEF0, sOF0, sER0, sOR0, sEF1, sOF1, sER1, sOR1);
        float bF = blF[lane], bR = blR[lane];
        if (m0) {
            float h0 = __half2float(hin[n0 * 32 + lane]);
            float aF0 = bF, aR0 = bR;
            #pragma unroll
            for (int k = 0; k < 32; ++k) {
                float fk = __shfl((k & 1) ? sOF0 : sEF0, k >> 1, 32);
                float rk = __shfl((k & 1) ? sOR0 : sER0, k >> 1, 32);
                float hk = __shfl(h0, k, 32);
                aF0 = fmaf(fk, WLF[k][lane], aF0);
                aF0 = fmaf(hk, WRF[k][lane], aF0);
                aR0 = fmaf(rk, WLR[k][lane], aR0);
                aR0 = fmaf(hk, WRR[k][lane], aR0);
            }
            hout[n0 * 32 + lane] = __float2half(fmaxf(aF0, 0.f) + fmaxf(aR0, 0.f));
        }
        if (m1) {
            float h1 = __half2float(hin[n1 * 32 + lane]);
            float aF1 = bF, aR1 = bR;
            #pragma unroll
            for (int k = 0; k < 32; ++k) {
                float fk = __shfl((k & 1) ? sOF1 : sEF1, k >> 1, 32);
                float rk = __shfl((k & 1) ? sOR1 : sER1, k >> 1, 32);
                float hk = __shfl(h1, k, 32);
                aF1 = fmaf(fk, WLF[k][lane], aF1);
                aF1 = fmaf(hk, WRF[k][lane], aF1);
                aR1 = fmaf(rk, WLR[k][lane], aR1);
                aR1 = fmaf(hk, WRR[k][lane], aR1);
            }
            hout[n1 * 32 + lane] = __float2half(fmaxf(aF1, 0.f) + fmaxf(aR1, 0.f));
        }
    }
}

__global__ void k_pair(const __half* __restrict__ h, const int* __restrict__ pos1,
                       __half* __restrict__ hp, int total) {
    int idx = blockIdx.x * blockDim.x + threadIdx.x;
    int stride = gridDim.x * blockDim.x;
    for (; idx < total; idx += stride) {
        int r = idx >> 5, k = idx & 31;
        int a = pos1[2 * r], b = pos1[2 * r + 1];
        hp[idx] = __float2half(__half2float(h[a * 32 + k]) * __half2float(h[b * 32 + k]));
    }
}

__global__ void k_final(const __half* __restrict__ h, const int* __restrict__ pos2,
                        const float* __restrict__ pw, const float* __restrict__ pb,
                        float* __restrict__ out, int m2) {
    int tid  = threadIdx.x;
    int lane = tid & 31;
    int i    = blockIdx.x * 8 + (tid >> 5);
    if (i >= m2) return;
    int p0 = pos2[2 * i], p1 = pos2[2 * i + 1];
    float v = __half2float(h[p0 * 32 + lane]) * __half2float(h[p1 * 32 + lane]) * pw[lane];
    #pragma unroll
    for (int o = 16; o > 0; o >>= 1) v += __shfl_xor(v, o, 32);
    if (lane == 0) out[i] = v + pb[0];
}

// ---------------- launch ----------------

extern "C" void kernel_launch(void* const* d_in, const int* in_sizes, int n_in,
                              void* d_out, int out_size, void* d_ws, size_t ws_size,
                              hipStream_t stream) {
    const int*   x      = (const int*)d_in[0];
    const int*   edge1  = (const int*)d_in[2];
    const int*   edge2  = (const int*)d_in[3];
    const int*   edge2r = (const int*)d_in[4];
    const int*   pos1   = (const int*)d_in[5];
    const int*   pos2   = (const int*)d_in[6];
    const float* emb    = (const float*)d_in[7];
    const float* gw     = (const float*)d_in[8];
    const float* gb     = (const float*)d_in[9];
    const float* gms    = (const float*)d_in[10];
    const float* c1wl   = (const float*)d_in[11];
    const float* c1bl   = (const float*)d_in[12];
    const float* c1wr   = (const float*)d_in[13];
    const float* c2wl   = (const float*)d_in[14];
    const float* c2bl   = (const float*)d_in[15];
    const float* c2wr   = (const float*)d_in[16];
    const float* c2rwl  = (const float*)d_in[17];
    const float* c2rbl  = (const float*)d_in[18];
    const float* c2rwr  = (const float*)d_in[19];
    const float* pw     = (const float*)d_in[20];
    const float* pb     = (const float*)d_in[21];
    float* out = (float*)d_out;

    char* ws = (char*)d_ws;
    __half* hA   = (__half*)(ws + OFF_HA);
    __half* hB   = (__half*)(ws + OFF_HB);
    int*   cnt   = (int*)(ws + OFF_HB);          // overlays hB, dead before k_sage_emb
    int*   csr1  = (int*)(ws + OFF_CSR1);
    int*   csr2  = (int*)(ws + OFF_CSR2);
    int*   csr2r = (int*)(ws + OFF_CSR2R);
    int*   off1  = (int*)(ws + OFF_OFF1);
    int*   off2  = (int*)(ws + OFF_OFF2);
    int*   off2r = (int*)(ws + OFF_OFF2R);
    int*   bsum  = (int*)(ws + OFF_BSUM);
    int*   hist  = (int*)(ws + OFF_HIST);
    float* wlp   = (float*)(ws + OFF_WLP);
    float* wrp   = (float*)(ws + OFF_WRP);
    float* bp    = (float*)(ws + OFF_BP);
    int*   mark  = (int*)(ws + OFF_MARK);

    // temp bucketed-edge arrays overlay hA (dead until k_sage writes hA)
    int* beF = (int*)(ws + OFF_HA);
    int* beR = (int*)(ws + OFF_HA + 12800000);
    int* be1 = (int*)(ws + OFF_HA);

    hipMemsetAsync(hist, 0, 512, stream);
    hipMemsetAsync(mark, 0, N2N * sizeof(int), stream);

    // --- GraphNorm stats from x-histogram + layer-1 weight fold; pos2 mark ---
    k_histx<<<256, 256, 0, stream>>>(x, hist, NN);
    k_prep<<<1, 256, 0, stream>>>(hist, emb, gw, gb, gms, c1wl, c1bl, c1wr, wlp, wrp, bp);
    k_mark<<<256, 256, 0, stream>>>(pos2, mark, MN);

    // --- CSR build: histogram -> scan -> bin (LDS cursors) -> per-bucket refine ---
    k_hist<<<3 * P_PART, 256, 0, stream>>>(edge2 + E2N, edge2r + E2N, edge1 + E1N, cnt);
    k_scanA<<<SCAN_NB, 256, 0, stream>>>(cnt, bsum);
    k_scanB<<<1, 256, 0, stream>>>(bsum, SCAN_NB);
    k_scanC<<<SCAN_NB, 256, 0, stream>>>(cnt, bsum);
    k_bfillFR<<<2 * P_PART, 256, 0, stream>>>(edge2, edge2 + E2N, edge2r, edge2r + E2N,
                                              cnt, beF, beR);
    k_bcsr2<<<2 * NBKT2, 256, 0, stream>>>(beF, beR, cnt, off2, csr2, off2r, csr2r);
    k_bfill1<<<P_PART, 256, 0, stream>>>(edge1, edge1 + E1N, cnt, be1);
    k_bcsr1<<<NBKT1, 256, 0, stream>>>(be1, cnt, off1, csr1);

    // --- conv1 layer 1: direct from emb via LDS -> h1 fp16 (clobbers cnt) ---
    k_sage_emb<<<6250, 256, 0, stream>>>(x, emb, hB, csr1, off1, wlp, bp, wrp, NN);

    // --- conv1 layer 2: hB -> hA fp16 (clobbers be temp, now dead) ---
    k_sage<<<2048, 256, 0, stream>>>(hB, hA, csr1, off1,
                                     c1wl + 1024, c1bl + 32, c1wr + 1024, NN);

    // --- pair features: hA (N rows) -> hB (N2 rows fp16; csr1 now dead) ---
    k_pair<<<2048, 256, 0, stream>>>(hA, pos1, hB, N2N * 32);

    // --- conv2 layer 1 (all nodes): hB -> hA ---
    k_sage2<<<2048, 256, 0, stream>>>(hB, hA, csr2, off2, csr2r, off2r,
        c2wl, c2bl, c2wr, c2rwl, c2rbl, c2rwr, (const int*)nullptr, N2N);

    // --- conv2 layer 2 (only pos2-referenced nodes): hA -> hB ---
    k_sage2<<<2048, 256, 0, stream>>>(hA, hB, csr2, off2, csr2r, off2r,
        c2wl + 1024, c2bl + 32, c2wr + 1024, c2rwl + 1024, c2rbl + 32, c2rwr + 1024,
        mark, N2N);

    // --- head ---
    k_final<<<(MN / 2) / 8, 256, 0, stream>>>(hB, pos2, pw, pb, out, MN / 2);
}